// Round 11
// baseline (310.637 us; speedup 1.0000x reference)
//
#include <hip/hip_runtime.h>
#include <cstdint>
#include <cstddef>
#include <math.h>

#define NEG_SLOPE 0.2f
#define DEGB 512
#define EB 4096            // edges per block in the bucketed CSR build

typedef unsigned short ushort_t;
typedef __attribute__((ext_vector_type(8))) short short8;      // bf16x8 MFMA operand
typedef __attribute__((ext_vector_type(4))) float f32x4;       // MFMA accumulator
typedef _Float16 half8 __attribute__((ext_vector_type(8)));    // fp16x8 row chunk
typedef _Float16 half2_t __attribute__((ext_vector_type(2)));  // fp16x2 packed

// f32 -> bf16 (RNE); bf16 -> f32 is shl 16.
__device__ __forceinline__ ushort_t f2bf(float f) {
    unsigned u = __float_as_uint(f);
    unsigned r = u + 0x7FFFu + ((u >> 16) & 1u);
    return (ushort_t)(r >> 16);
}
__device__ __forceinline__ float bf2f(ushort_t h) {
    return __uint_as_float(((unsigned)h) << 16);
}
__device__ __forceinline__ ushort_t f2h(float f) {
    _Float16 h = (_Float16)f;
    return *(ushort_t*)&h;
}

__device__ __forceinline__ float dot2acc(half2_t a, half2_t b, float c) {
#if __has_builtin(__builtin_amdgcn_fdot2)
    return __builtin_amdgcn_fdot2(a, b, c, false);
#else
    return c + (float)a[0] * (float)b[0] + (float)a[1] * (float)b[1];
#endif
}

// DPP quad butterfly add: p += lane[p ^ k] for k in {1,2} within each quad.
// quad_perm [1,0,3,2] = 0xB1 (xor1), [2,3,0,1] = 0x4E (xor2).
template<int CTRL>
__device__ __forceinline__ float dpp_add(float p) {
    int t = __builtin_amdgcn_update_dpp(0, __builtin_bit_cast(int, p),
                                        CTRL, 0xF, 0xF, true);
    return p + __builtin_bit_cast(float, t);
}

// lane^4 butterfly add via ds_swizzle (BitMode: xor_mask<<10 | and 0x1F)
__device__ __forceinline__ float swz4_add(float p) {
    int t = __builtin_amdgcn_ds_swizzle(__builtin_bit_cast(int, p), 0x101F);
    return p + __builtin_bit_cast(float, t);
}

__device__ __forceinline__ int wave_incl_scan(int v, int lane) {
    #pragma unroll
    for (int o = 1; o < 64; o <<= 1) {
        int t = __shfl_up(v, o, 64);
        if (lane >= o) v += t;
    }
    return v;
}

// ================= bucketed CSR build (7 kernels, fused stages) =================
// R7/R8's single-kernel grid-barrier build stalled ~33us/barrier (cross-XCD
// spin) — abandoned. Stages sharing a block decomposition are fused instead.

// pass A: per-4096-edge-block 256-bin histogram of dst>>8
__global__ void bucket_hist(const int* __restrict__ ei, int E, int Et,
                            int* __restrict__ blkcnt) {
    __shared__ int cnt[256];
    int t = threadIdx.x;
    cnt[t] = 0;
    __syncthreads();
    int e0 = blockIdx.x * EB;
    #pragma unroll
    for (int it = 0; it < EB / 256; ++it) {
        int e = e0 + it * 256 + t;
        if (e < Et) {
            int d = (e < E) ? ei[E + e] : (e - E);
            atomicAdd(&cnt[d >> 8], 1);
        }
    }
    __syncthreads();
    blkcnt[blockIdx.x * 256 + t] = cnt[t];
}

// pass B1: for each bucket (column), exclusive scan over blocks; total -> btot
__global__ void colscan(int* __restrict__ blkcnt, int nblk, int* __restrict__ btot) {
    int b = blockIdx.x;             // bucket 0..255
    int lane = threadIdx.x;         // 64 threads
    int running = 0;
    for (int base = 0; base < nblk; base += 64) {
        int idx = base + lane;
        int v = (idx < nblk) ? blkcnt[idx * 256 + b] : 0;
        int incl = wave_incl_scan(v, lane);
        if (idx < nblk) blkcnt[idx * 256 + b] = running + incl - v;
        running += __shfl(incl, 63, 64);
    }
    if (lane == 0) btot[b] = running;
}

// pass B2: exclusive scan of bucket totals -> bucket bases
__global__ void bucketscan(const int* __restrict__ btot, int* __restrict__ bbase) {
    __shared__ int tmp[256];
    int t = threadIdx.x;
    int v = btot[t];
    tmp[t] = v;
    __syncthreads();
    for (int o = 1; o < 256; o <<= 1) {
        int x = (t >= o) ? tmp[t - o] : 0;
        __syncthreads();
        tmp[t] += x;
        __syncthreads();
    }
    bbase[t] = tmp[t] - v;
}

// pass C: scatter packed edges into bucket-grouped ebuf.
// pack = src | (dst&255)<<17  (valid: N=50000 < 2^17)
__global__ void bucket_scatter(const int* __restrict__ ei, int E, int Et,
                               const int* __restrict__ blkrel,
                               const int* __restrict__ bbase,
                               unsigned* __restrict__ ebuf) {
    __shared__ int base_l[256];
    __shared__ int cnt[256];
    int t = threadIdx.x;
    base_l[t] = bbase[t] + blkrel[blockIdx.x * 256 + t];
    cnt[t] = 0;
    __syncthreads();
    int e0 = blockIdx.x * EB;
    #pragma unroll
    for (int it = 0; it < EB / 256; ++it) {
        int e = e0 + it * 256 + t;
        if (e < Et) {
            int s, d;
            if (e < E) { s = ei[e]; d = ei[E + e]; }
            else       { s = d = e - E; }
            int b = d >> 8;
            int r = atomicAdd(&cnt[b], 1);
            ebuf[base_l[b] + r] = (unsigned)s | (((unsigned)d & 255u) << 17);
        }
    }
}

// pass D (fused csr_count + scan1 + deg_hist): per-bucket degree counts,
// block-local prefix (rowstart partial), degree histogram.
__global__ void bucket_deg_scan_hist(const unsigned* __restrict__ ebuf,
                                     const int* __restrict__ bbase,
                                     const int* __restrict__ btot,
                                     int N, int* __restrict__ deg,
                                     int* __restrict__ rowstart,
                                     int* __restrict__ partials,
                                     int* __restrict__ dhist) {
    __shared__ int dcnt[256];
    __shared__ int tmp[256];
    __shared__ int h[DEGB];
    int b = blockIdx.x, t = threadIdx.x;
    dcnt[t] = 0;
    h[t] = 0; h[t + 256] = 0;
    __syncthreads();
    int s0 = bbase[b], c = btot[b];
    for (int i = t; i < c; i += 256)
        atomicAdd(&dcnt[ebuf[s0 + i] >> 17], 1);
    __syncthreads();
    int node = b * 256 + t;
    int dv = dcnt[t];
    if (node < N) deg[node] = dv;
    tmp[t] = dv;
    __syncthreads();
    for (int o = 1; o < 256; o <<= 1) {
        int x = (t >= o) ? tmp[t - o] : 0;
        __syncthreads();
        tmp[t] += x;
        __syncthreads();
    }
    if (node < N) rowstart[node] = tmp[t] - dv;    // block-local exclusive
    if (t == 255) partials[b] = tmp[255];
    if (node < N) {
        int dc = dv < DEGB - 1 ? dv : DEGB - 1;
        atomicAdd(&h[dc], 1);
    }
    __syncthreads();
    int c0 = h[t];       if (c0) atomicAdd(&dhist[t], c0);
    int c1 = h[t + 256]; if (c1) atomicAdd(&dhist[t + 256], c1);
}

// pass E (fused scan23 + deg_scan): blocks 0..nbkt-1 finalize rowstart;
// block nbkt scans the 512-bin degree histogram -> descending dstart.
__global__ void finalize_scans(int* __restrict__ rowstart,
                               const int* __restrict__ partials, int nbkt, int N,
                               const int* __restrict__ dhist,
                               int* __restrict__ dstart) {
    __shared__ int tmp[DEGB];       // 512
    int t = threadIdx.x;            // 512 threads
    int b = blockIdx.x;
    if (b < nbkt) {
        if (t < 256) tmp[t] = (t < nbkt) ? partials[t] : 0;
        __syncthreads();
        for (int o = 1; o < 256; o <<= 1) {
            int x = (t < 256 && t >= o) ? tmp[t - o] : 0;
            __syncthreads();
            if (t < 256) tmp[t] += x;
            __syncthreads();
        }
        int off = (b > 0) ? tmp[b - 1] : 0;
        int node = b * 256 + t;
        if (t < 256 && node < N) rowstart[node] += off;
    } else {
        int v = dhist[t];
        tmp[t] = v;
        __syncthreads();
        for (int o = 1; o < DEGB; o <<= 1) {
            int x = (t >= o) ? tmp[t - o] : 0;
            __syncthreads();
            tmp[t] += x;
            __syncthreads();
        }
        dstart[t] = tmp[DEGB - 1] - tmp[t];
    }
}

// pass F (fused csr_scatter2 + deg_scatter): CSR scatter with LDS cursors +
// degree-sorted 16B descriptor {node, rowstart, deg} scatter.
__global__ void csr_perm_scatter(const unsigned* __restrict__ ebuf,
                                 const int* __restrict__ bbase,
                                 const int* __restrict__ btot,
                                 const int* __restrict__ rowstart,
                                 const int* __restrict__ deg, int N,
                                 int* __restrict__ dstart,
                                 int* __restrict__ csr_src,
                                 int4* __restrict__ desc) {
    __shared__ int cur[256];
    __shared__ int h[DEGB];
    __shared__ int base[DEGB];
    int b = blockIdx.x, t = threadIdx.x;
    int node = b * 256 + t;
    int rs = (node < N) ? rowstart[node] : 0;
    cur[t] = rs;
    h[t] = 0; h[t + 256] = 0;
    __syncthreads();
    int s0 = bbase[b], c = btot[b];
    for (int i = t; i < c; i += 256) {
        unsigned v = ebuf[s0 + i];
        int pos = atomicAdd(&cur[v >> 17], 1);
        csr_src[pos] = (int)(v & 0x1FFFFu);
    }
    int dv = (node < N) ? deg[node] : 0;
    int dc = dv < DEGB - 1 ? dv : DEGB - 1;
    int r = 0;
    if (node < N) r = atomicAdd(&h[dc], 1);
    __syncthreads();
    int c0 = h[t];       if (c0) base[t]       = atomicAdd(&dstart[t], c0);
    int c1 = h[t + 256]; if (c1) base[t + 256] = atomicAdd(&dstart[t + 256], c1);
    __syncthreads();
    if (node < N) desc[base[dc] + r] = make_int4(node, rs, dv, 0);
}

// ---------------- split-bf16 MFMA GEMM ----------------
// out_virtual[N x 2*MOUT] = A[N x 128] @ [Wl | Wr].
// A@W ~= Ah@Wh + Ah@Wlo + Al@Wh  (lo*lo dropped, ~2^-18 relative).
// Both output tables written as fp16 (attention reads them).
template<int MOUT, bool CONVA>
__global__ __launch_bounds__(256) void gemm_mfma(const ushort_t* __restrict__ Ah,
                                                 const ushort_t* __restrict__ Al,
                                                 const float* __restrict__ Af,
                                                 const float* __restrict__ Wl,
                                                 const float* __restrict__ Wr,
                                                 ushort_t* __restrict__ xlh,
                                                 ushort_t* __restrict__ xrh, int N) {
    __shared__ __align__(16) ushort_t Bh[8192];   // 16 KB
    __shared__ __align__(16) ushort_t Bl[8192];   // 16 KB
    const int tid   = threadIdx.x;
    const int row0  = blockIdx.x * 128;
    const int col0v = blockIdx.y * 64;
    const bool isR  = col0v >= MOUT;
    const float* W  = isR ? Wr : Wl;
    const int wcol0 = isR ? (col0v - MOUT) : col0v;
    ushort_t* OUT   = isR ? xrh : xlh;

    #pragma unroll
    for (int i = 0; i < 8; ++i) {
        int idx = tid * 8 + i;
        int k   = idx >> 4;
        int c4  = (idx & 15) * 4;
        float4 w = *(const float4*)(W + (size_t)k * MOUT + wcol0 + c4);
        float wv[4] = {w.x, w.y, w.z, w.w};
        int q = k >> 5, quad = (k >> 3) & 3, j = k & 7;
        #pragma unroll
        for (int e = 0; e < 4; ++e) {
            int c = c4 + e;
            int t = c >> 4;
            int l = (quad << 4) | (c & 15);
            int pos = ((t * 4 + q) * 64 + l) * 8 + j;
            ushort_t hb = f2bf(wv[e]);
            Bh[pos] = hb;
            Bl[pos] = f2bf(wv[e] - bf2f(hb));
        }
    }
    __syncthreads();

    const int wv_  = tid >> 6;
    const int lane = tid & 63;
    const int m    = lane & 15;
    const int quad = lane >> 4;
    const int wrow0 = row0 + wv_ * 32;

    f32x4 acc[2][4] = {};

    for (int q = 0; q < 4; ++q) {
        short8 ahf[2], alf[2];
        #pragma unroll
        for (int r = 0; r < 2; ++r) {
            int row = wrow0 + 16 * r + m;
            row = row < N ? row : N - 1;
            size_t off = (size_t)row * 128 + q * 32 + quad * 8;
            if constexpr (CONVA) {
                float4 f0 = *(const float4*)(Af + off);
                float4 f1 = *(const float4*)(Af + off + 4);
                float fv[8] = {f0.x, f0.y, f0.z, f0.w, f1.x, f1.y, f1.z, f1.w};
                short ah[8], al[8];
                #pragma unroll
                for (int e = 0; e < 8; ++e) {
                    ushort_t hb = f2bf(fv[e]);
                    ah[e] = (short)hb;
                    al[e] = (short)f2bf(fv[e] - bf2f(hb));
                }
                ahf[r] = short8{ah[0],ah[1],ah[2],ah[3],ah[4],ah[5],ah[6],ah[7]};
                alf[r] = short8{al[0],al[1],al[2],al[3],al[4],al[5],al[6],al[7]};
            } else {
                ahf[r] = *(const short8*)(Ah + off);
                alf[r] = *(const short8*)(Al + off);
            }
        }
        #pragma unroll
        for (int t = 0; t < 4; ++t) {
            int base = ((t * 4 + q) * 64 + lane) * 8;
            short8 bh = *(const short8*)(Bh + base);
            short8 bl = *(const short8*)(Bl + base);
            #pragma unroll
            for (int r = 0; r < 2; ++r) {
                acc[r][t] = __builtin_amdgcn_mfma_f32_16x16x32_bf16(ahf[r], bh, acc[r][t], 0, 0, 0);
                acc[r][t] = __builtin_amdgcn_mfma_f32_16x16x32_bf16(ahf[r], bl, acc[r][t], 0, 0, 0);
                acc[r][t] = __builtin_amdgcn_mfma_f32_16x16x32_bf16(alf[r], bh, acc[r][t], 0, 0, 0);
            }
        }
    }

    #pragma unroll
    for (int r = 0; r < 2; ++r)
        #pragma unroll
        for (int i = 0; i < 4; ++i) {
            int row = wrow0 + 16 * r + quad * 4 + i;
            if (row < N) {
                #pragma unroll
                for (int t = 0; t < 4; ++t)
                    OUT[(size_t)row * MOUT + wcol0 + t * 16 + m] = f2h(acc[r][t][i]);
            }
        }
}

// ---------------- fused per-node attention: one 16-lane group per node ----------------
// R11: DR 5 -> 10. Latency arithmetic: gathered row ~600cy (L3), per-edge
// compute ~30cy -> need ~20 edges in flight per group; DR=5 covered 5 and
// measured VALUBusy plateaued ~60-70% (ring-starved). DR=10 costs ~+25 VGPR
// (rbuf+ibuf) -> ~90, still >= 5 waves/SIMD cap, above the ~3 actually
// resident — pure MLP gain. deg<DR prologue over-fetch is clamped to the
// last edge (same cacheline, cheap).
template<int H, int C, bool ELU, int OMODE>
__global__ __launch_bounds__(512) void node_attn(const ushort_t* __restrict__ xlh,
                                                 const ushort_t* __restrict__ xrh,
                                                 const float* __restrict__ att,
                                                 const float* __restrict__ bias,
                                                 const int4* __restrict__ desc,
                                                 const int* __restrict__ csr_src,
                                                 int N, float* __restrict__ out,
                                                 ushort_t* __restrict__ outh,
                                                 ushort_t* __restrict__ outl) {
    constexpr int HC  = H * C;          // 128 / 64
    constexpr int VPT = 8;
    constexpr int LPG = HC / VPT;       // lanes per group: 16 / 8
    constexpr int GPW = 64 / LPG;       // groups (nodes) per wave: 4 / 8
    constexpr int GROUP = C / VPT;      // lanes per head: 4 / 8
    constexpr int DR  = 10;             // gather ring depth per group

    const int lane = threadIdx.x & 63;
    const int wv   = threadIdx.x >> 6;
    const int gid  = lane / LPG;
    const int lig  = lane % LPG;
    const int ch0  = lig * VPT;

    const int s = (blockIdx.x * 8 + wv) * GPW + gid;
    if (s >= N) return;

    // per-kernel invariants
    half2_t a2[4];
    {
        float4 u0 = *(const float4*)(att + ch0);
        float4 u1 = *(const float4*)(att + ch0 + 4);
        a2[0] = half2_t{(_Float16)u0.x, (_Float16)u0.y};
        a2[1] = half2_t{(_Float16)u0.z, (_Float16)u0.w};
        a2[2] = half2_t{(_Float16)u1.x, (_Float16)u1.y};
        a2[3] = half2_t{(_Float16)u1.z, (_Float16)u1.w};
    }
    float bias8[VPT];
    {
        float4 b0 = *(const float4*)(bias + ch0);
        float4 b1 = *(const float4*)(bias + ch0 + 4);
        bias8[0]=b0.x; bias8[1]=b0.y; bias8[2]=b0.z; bias8[3]=b0.w;
        bias8[4]=b1.x; bias8[5]=b1.y; bias8[6]=b1.z; bias8[7]=b1.w;
    }
    const half2_t c02 = half2_t{(_Float16)NEG_SLOPE, (_Float16)NEG_SLOPE};

    const int4 dsc = desc[s];
    const int n  = dsc.x;
    const int j0 = dsc.y;
    const int dg = dsc.z;               // >= 1 (self-loop)

    half8 xrv = *(const half8*)(xrh + (size_t)n * HC + ch0);

    auto ldidx = [&](int e) {
        int ee = e < dg ? e : dg - 1;   // clamp: harmless duplicate loads
        return csr_src[j0 + ee];
    };
    auto ldrow = [&](int idx) -> half8 {
        return *(const half8*)(xlh + (size_t)(unsigned)idx * HC + ch0);  // 16 B
    };

    float d = 0.f;
    float acc[VPT] = {};

    auto process = [&](half8 v) {
        float p = 0.f;
        #pragma unroll
        for (int i = 0; i < 4; ++i) {
            half2_t v2 = half2_t{v[2 * i], v[2 * i + 1]};
            half2_t x2 = half2_t{xrv[2 * i], xrv[2 * i + 1]};
            half2_t m2 = v2 + x2;                                 // v_pk_add_f16
            half2_t lr = __builtin_elementwise_max(m2, c02 * m2); // pk_mul+pk_max
            p = dot2acc(lr, a2[i], p);                            // v_dot2_f32_f16
        }
        // head reduce: quad DPP (lanes of one head are an aligned quad),
        // plus lane^4 swizzle when the head spans 8 lanes (layer 3).
        if constexpr (GROUP >= 2) p = dpp_add<0xB1>(p);  // xor 1
        if constexpr (GROUP >= 4) p = dpp_add<0x4E>(p);  // xor 2
        if constexpr (GROUP >= 8) p = swz4_add(p);       // xor 4
        float pe = __expf(p);
        d += pe;
        #pragma unroll
        for (int i = 0; i < VPT; ++i)
            acc[i] += pe * (float)v[i];                           // fma_mix-able
    };

    // ring prologue: indices, then rows (+ next indices)
    int   ibuf[DR];
    half8 rbuf[DR];
    #pragma unroll
    for (int k = 0; k < DR; ++k) ibuf[k] = ldidx(k);
    #pragma unroll
    for (int k = 0; k < DR; ++k) {
        rbuf[k] = ldrow(ibuf[k]);
        ibuf[k] = ldidx(k + DR);
    }

    int e = 0;
    for (; e + DR <= dg; e += DR) {      // group-uniform trip count
        #pragma unroll
        for (int k = 0; k < DR; ++k) {
            half8 v = rbuf[k];
            rbuf[k] = ldrow(ibuf[k]);
            ibuf[k] = ldidx(e + k + 2 * DR);
            process(v);
        }
    }
    #pragma unroll
    for (int k = 0; k < DR; ++k)
        if (e + k < dg) process(rbuf[k]);

    // epilogue: d and acc are lane-local (d uniform across the head's lanes)
    float inv = 1.f / d;
    float vv[VPT];
    #pragma unroll
    for (int i = 0; i < VPT; ++i) {
        float v = acc[i] * inv + bias8[i];
        if (ELU) v = v > 0.f ? v : (__expf(v) - 1.f);
        vv[i] = v;
    }
    if (OMODE == 0) {
        *(float4*)(out + (size_t)n * HC + ch0) =
            make_float4(vv[0], vv[1], vv[2], vv[3]);
        *(float4*)(out + (size_t)n * HC + ch0 + 4) =
            make_float4(vv[4], vv[5], vv[6], vv[7]);
    } else {
        ushort_t hb[VPT], lb[VPT];
        #pragma unroll
        for (int i = 0; i < VPT; ++i) {
            hb[i] = f2bf(vv[i]);
            lb[i] = f2bf(vv[i] - bf2f(hb[i]));
        }
        *(ushort4*)(outh + (size_t)n * HC + ch0) =
            ushort4{hb[0], hb[1], hb[2], hb[3]};
        *(ushort4*)(outh + (size_t)n * HC + ch0 + 4) =
            ushort4{hb[4], hb[5], hb[6], hb[7]};
        *(ushort4*)(outl + (size_t)n * HC + ch0) =
            ushort4{lb[0], lb[1], lb[2], lb[3]};
        *(ushort4*)(outl + (size_t)n * HC + ch0 + 4) =
            ushort4{lb[4], lb[5], lb[6], lb[7]};
    }
}

// ---------------- launch ----------------
extern "C" void kernel_launch(void* const* d_in, const int* in_sizes, int n_in,
                              void* d_out, int out_size, void* d_ws, size_t ws_size,
                              hipStream_t stream) {
    const float* x   = (const float*)d_in[0];
    const int*   ei  = (const int*)d_in[1];
    const float* Wl1 = (const float*)d_in[2];
    const float* Wr1 = (const float*)d_in[3];
    const float* a1  = (const float*)d_in[4];
    const float* b1  = (const float*)d_in[5];
    const float* Wl2 = (const float*)d_in[6];
    const float* Wr2 = (const float*)d_in[7];
    const float* a2  = (const float*)d_in[8];
    const float* b2  = (const float*)d_in[9];
    const float* Wl3 = (const float*)d_in[10];
    const float* Wr3 = (const float*)d_in[11];
    const float* a3  = (const float*)d_in[12];
    const float* b3  = (const float*)d_in[13];

    const int N  = in_sizes[0] / 128;   // 50000
    const int E  = in_sizes[1] / 2;     // 800000
    const int Et = E + N;               // 850000
    const int nb = (N + 255) / 256;     // 196 (= bucket count)

    char* p = (char*)d_ws;
    auto alloc = [&](size_t bytes) -> void* {
        void* r = (void*)p;
        p += (bytes + 255) & ~(size_t)255;
        return r;
    };
    const int ebBlocks = (Et + EB - 1) / EB;    // 208
    int*      csr_src  = (int*)alloc((size_t)Et * 4 + 256);
    unsigned* ebuf     = (unsigned*)alloc((size_t)Et * 4);
    int*      blkcnt   = (int*)alloc((size_t)ebBlocks * 256 * 4);
    int*      btot     = (int*)alloc(256 * 4);
    int*      bbase    = (int*)alloc(256 * 4);
    int*      deg      = (int*)alloc((size_t)N * 4);
    int*      rowstart = (int*)alloc((size_t)N * 4);
    int*      partials = (int*)alloc((size_t)nb * 4);
    int4*     desc     = (int4*)alloc((size_t)N * 16);
    int*      dhist    = (int*)alloc((size_t)DEGB * 4);
    int*      dstart   = (int*)alloc((size_t)DEGB * 4);
    ushort_t* xlh      = (ushort_t*)alloc((size_t)N * 128 * 2);  // fp16 gather table
    ushort_t* xrh      = (ushort_t*)alloc((size_t)N * 128 * 2);  // fp16 target table
    ushort_t* Ah       = (ushort_t*)alloc((size_t)N * 128 * 2);
    ushort_t* Al       = (ushort_t*)alloc((size_t)N * 128 * 2);

    const int rowBlocks    = (N + 127) / 128;   // 391
    const int nodeBlocks12 = (N + 31) / 32;     // 1 node per 16-lane group
    const int nodeBlocks3  = (N + 63) / 64;     // 1 node per 8-lane group

    // ---- bucketed CSR by dst + degree-sorted node descriptors (once; reused) ----
    hipMemsetAsync(dhist, 0, (size_t)DEGB * 4, stream);
    bucket_hist<<<ebBlocks, 256, 0, stream>>>(ei, E, Et, blkcnt);
    colscan<<<256, 64, 0, stream>>>(blkcnt, ebBlocks, btot);
    bucketscan<<<1, 256, 0, stream>>>(btot, bbase);
    bucket_scatter<<<ebBlocks, 256, 0, stream>>>(ei, E, Et, blkcnt, bbase, ebuf);
    bucket_deg_scan_hist<<<nb, 256, 0, stream>>>(ebuf, bbase, btot, N,
                                                 deg, rowstart, partials, dhist);
    finalize_scans<<<nb + 1, DEGB, 0, stream>>>(rowstart, partials, nb, N,
                                                dhist, dstart);
    csr_perm_scatter<<<nb, 256, 0, stream>>>(ebuf, bbase, btot, rowstart, deg, N,
                                             dstart, csr_src, desc);

    // ---- layer 1: 128 -> 4x32, concat, ELU (A converted inline from f32) ----
    gemm_mfma<128, true><<<dim3(rowBlocks, 4), 256, 0, stream>>>(
        nullptr, nullptr, x, Wl1, Wr1, xlh, xrh, N);
    node_attn<4, 32, true, 1><<<nodeBlocks12, 512, 0, stream>>>(
        xlh, xrh, a1, b1, desc, csr_src, N, nullptr, Ah, Al);

    // ---- layer 2: 128 -> 4x32, concat, ELU ----
    gemm_mfma<128, false><<<dim3(rowBlocks, 4), 256, 0, stream>>>(
        Ah, Al, nullptr, Wl2, Wr2, xlh, xrh, N);
    node_attn<4, 32, true, 1><<<nodeBlocks12, 512, 0, stream>>>(
        xlh, xrh, a2, b2, desc, csr_src, N, nullptr, Ah, Al);

    // ---- layer 3: 128 -> 64, heads=1, concat=False ----
    float* out = (float*)d_out;
    gemm_mfma<64, false><<<dim3(rowBlocks, 2), 256, 0, stream>>>(
        Ah, Al, nullptr, Wl3, Wr3, xlh, xrh, N);
    node_attn<1, 64, false, 0><<<nodeBlocks3, 512, 0, stream>>>(
        xlh, xrh, a3, b3, desc, csr_src, N, out, nullptr, nullptr);
}

// Round 12
// 286.482 us; speedup vs baseline: 1.0843x; 1.0843x over previous
//
#include <hip/hip_runtime.h>
#include <cstdint>
#include <cstddef>
#include <math.h>

#define NEG_SLOPE 0.2f
#define DEGB 512
#define EB 4096            // edges per block in the bucketed CSR build

typedef unsigned short ushort_t;
typedef __attribute__((ext_vector_type(8))) short short8;      // bf16x8 MFMA operand
typedef __attribute__((ext_vector_type(4))) float f32x4;       // MFMA accumulator
typedef _Float16 half8 __attribute__((ext_vector_type(8)));    // fp16x8 row chunk
typedef _Float16 half2_t __attribute__((ext_vector_type(2)));  // fp16x2 packed

// f32 -> bf16 (RNE); bf16 -> f32 is shl 16.
__device__ __forceinline__ ushort_t f2bf(float f) {
    unsigned u = __float_as_uint(f);
    unsigned r = u + 0x7FFFu + ((u >> 16) & 1u);
    return (ushort_t)(r >> 16);
}
__device__ __forceinline__ float bf2f(ushort_t h) {
    return __uint_as_float(((unsigned)h) << 16);
}
__device__ __forceinline__ ushort_t f2h(float f) {
    _Float16 h = (_Float16)f;
    return *(ushort_t*)&h;
}

__device__ __forceinline__ float dot2acc(half2_t a, half2_t b, float c) {
#if __has_builtin(__builtin_amdgcn_fdot2)
    return __builtin_amdgcn_fdot2(a, b, c, false);
#else
    return c + (float)a[0] * (float)b[0] + (float)a[1] * (float)b[1];
#endif
}

// DPP quad butterfly add: p += lane[p ^ k] for k in {1,2} within each quad.
// quad_perm [1,0,3,2] = 0xB1 (xor1), [2,3,0,1] = 0x4E (xor2).
template<int CTRL>
__device__ __forceinline__ float dpp_add(float p) {
    int t = __builtin_amdgcn_update_dpp(0, __builtin_bit_cast(int, p),
                                        CTRL, 0xF, 0xF, true);
    return p + __builtin_bit_cast(float, t);
}

// lane^4 butterfly add via ds_swizzle (BitMode: xor_mask<<10 | and 0x1F)
__device__ __forceinline__ float swz4_add(float p) {
    int t = __builtin_amdgcn_ds_swizzle(__builtin_bit_cast(int, p), 0x101F);
    return p + __builtin_bit_cast(float, t);
}

__device__ __forceinline__ int wave_incl_scan(int v, int lane) {
    #pragma unroll
    for (int o = 1; o < 64; o <<= 1) {
        int t = __shfl_up(v, o, 64);
        if (lane >= o) v += t;
    }
    return v;
}

// ================= bucketed CSR build (7 kernels, fused stages) =================
// R7/R8's single-kernel grid-barrier build stalled ~33us/barrier (cross-XCD
// spin) — abandoned. Stages sharing a block decomposition are fused instead.

// pass A: per-4096-edge-block 256-bin histogram of dst>>8
__global__ void bucket_hist(const int* __restrict__ ei, int E, int Et,
                            int* __restrict__ blkcnt) {
    __shared__ int cnt[256];
    int t = threadIdx.x;
    cnt[t] = 0;
    __syncthreads();
    int e0 = blockIdx.x * EB;
    #pragma unroll
    for (int it = 0; it < EB / 256; ++it) {
        int e = e0 + it * 256 + t;
        if (e < Et) {
            int d = (e < E) ? ei[E + e] : (e - E);
            atomicAdd(&cnt[d >> 8], 1);
        }
    }
    __syncthreads();
    blkcnt[blockIdx.x * 256 + t] = cnt[t];
}

// pass B1: for each bucket (column), exclusive scan over blocks; total -> btot
__global__ void colscan(int* __restrict__ blkcnt, int nblk, int* __restrict__ btot) {
    int b = blockIdx.x;             // bucket 0..255
    int lane = threadIdx.x;         // 64 threads
    int running = 0;
    for (int base = 0; base < nblk; base += 64) {
        int idx = base + lane;
        int v = (idx < nblk) ? blkcnt[idx * 256 + b] : 0;
        int incl = wave_incl_scan(v, lane);
        if (idx < nblk) blkcnt[idx * 256 + b] = running + incl - v;
        running += __shfl(incl, 63, 64);
    }
    if (lane == 0) btot[b] = running;
}

// pass B2: exclusive scan of bucket totals -> bucket bases
__global__ void bucketscan(const int* __restrict__ btot, int* __restrict__ bbase) {
    __shared__ int tmp[256];
    int t = threadIdx.x;
    int v = btot[t];
    tmp[t] = v;
    __syncthreads();
    for (int o = 1; o < 256; o <<= 1) {
        int x = (t >= o) ? tmp[t - o] : 0;
        __syncthreads();
        tmp[t] += x;
        __syncthreads();
    }
    bbase[t] = tmp[t] - v;
}

// pass C: scatter packed edges into bucket-grouped ebuf.
// pack = src | (dst&255)<<17  (valid: N=50000 < 2^17)
__global__ void bucket_scatter(const int* __restrict__ ei, int E, int Et,
                               const int* __restrict__ blkrel,
                               const int* __restrict__ bbase,
                               unsigned* __restrict__ ebuf) {
    __shared__ int base_l[256];
    __shared__ int cnt[256];
    int t = threadIdx.x;
    base_l[t] = bbase[t] + blkrel[blockIdx.x * 256 + t];
    cnt[t] = 0;
    __syncthreads();
    int e0 = blockIdx.x * EB;
    #pragma unroll
    for (int it = 0; it < EB / 256; ++it) {
        int e = e0 + it * 256 + t;
        if (e < Et) {
            int s, d;
            if (e < E) { s = ei[e]; d = ei[E + e]; }
            else       { s = d = e - E; }
            int b = d >> 8;
            int r = atomicAdd(&cnt[b], 1);
            ebuf[base_l[b] + r] = (unsigned)s | (((unsigned)d & 255u) << 17);
        }
    }
}

// pass D (fused csr_count + scan1 + deg_hist): per-bucket degree counts,
// block-local prefix (rowstart partial), degree histogram.
__global__ void bucket_deg_scan_hist(const unsigned* __restrict__ ebuf,
                                     const int* __restrict__ bbase,
                                     const int* __restrict__ btot,
                                     int N, int* __restrict__ deg,
                                     int* __restrict__ rowstart,
                                     int* __restrict__ partials,
                                     int* __restrict__ dhist) {
    __shared__ int dcnt[256];
    __shared__ int tmp[256];
    __shared__ int h[DEGB];
    int b = blockIdx.x, t = threadIdx.x;
    dcnt[t] = 0;
    h[t] = 0; h[t + 256] = 0;
    __syncthreads();
    int s0 = bbase[b], c = btot[b];
    for (int i = t; i < c; i += 256)
        atomicAdd(&dcnt[ebuf[s0 + i] >> 17], 1);
    __syncthreads();
    int node = b * 256 + t;
    int dv = dcnt[t];
    if (node < N) deg[node] = dv;
    tmp[t] = dv;
    __syncthreads();
    for (int o = 1; o < 256; o <<= 1) {
        int x = (t >= o) ? tmp[t - o] : 0;
        __syncthreads();
        tmp[t] += x;
        __syncthreads();
    }
    if (node < N) rowstart[node] = tmp[t] - dv;    // block-local exclusive
    if (t == 255) partials[b] = tmp[255];
    if (node < N) {
        int dc = dv < DEGB - 1 ? dv : DEGB - 1;
        atomicAdd(&h[dc], 1);
    }
    __syncthreads();
    int c0 = h[t];       if (c0) atomicAdd(&dhist[t], c0);
    int c1 = h[t + 256]; if (c1) atomicAdd(&dhist[t + 256], c1);
}

// pass E (fused scan23 + deg_scan): blocks 0..nbkt-1 finalize rowstart;
// block nbkt scans the 512-bin degree histogram -> descending dstart.
__global__ void finalize_scans(int* __restrict__ rowstart,
                               const int* __restrict__ partials, int nbkt, int N,
                               const int* __restrict__ dhist,
                               int* __restrict__ dstart) {
    __shared__ int tmp[DEGB];       // 512
    int t = threadIdx.x;            // 512 threads
    int b = blockIdx.x;
    if (b < nbkt) {
        if (t < 256) tmp[t] = (t < nbkt) ? partials[t] : 0;
        __syncthreads();
        for (int o = 1; o < 256; o <<= 1) {
            int x = (t < 256 && t >= o) ? tmp[t - o] : 0;
            __syncthreads();
            if (t < 256) tmp[t] += x;
            __syncthreads();
        }
        int off = (b > 0) ? tmp[b - 1] : 0;
        int node = b * 256 + t;
        if (t < 256 && node < N) rowstart[node] += off;
    } else {
        int v = dhist[t];
        tmp[t] = v;
        __syncthreads();
        for (int o = 1; o < DEGB; o <<= 1) {
            int x = (t >= o) ? tmp[t - o] : 0;
            __syncthreads();
            tmp[t] += x;
            __syncthreads();
        }
        dstart[t] = tmp[DEGB - 1] - tmp[t];
    }
}

// pass F (fused csr_scatter2 + deg_scatter): CSR scatter with LDS cursors +
// degree-sorted 16B descriptor {node, rowstart, deg} scatter.
__global__ void csr_perm_scatter(const unsigned* __restrict__ ebuf,
                                 const int* __restrict__ bbase,
                                 const int* __restrict__ btot,
                                 const int* __restrict__ rowstart,
                                 const int* __restrict__ deg, int N,
                                 int* __restrict__ dstart,
                                 int* __restrict__ csr_src,
                                 int4* __restrict__ desc) {
    __shared__ int cur[256];
    __shared__ int h[DEGB];
    __shared__ int base[DEGB];
    int b = blockIdx.x, t = threadIdx.x;
    int node = b * 256 + t;
    int rs = (node < N) ? rowstart[node] : 0;
    cur[t] = rs;
    h[t] = 0; h[t + 256] = 0;
    __syncthreads();
    int s0 = bbase[b], c = btot[b];
    for (int i = t; i < c; i += 256) {
        unsigned v = ebuf[s0 + i];
        int pos = atomicAdd(&cur[v >> 17], 1);
        csr_src[pos] = (int)(v & 0x1FFFFu);
    }
    int dv = (node < N) ? deg[node] : 0;
    int dc = dv < DEGB - 1 ? dv : DEGB - 1;
    int r = 0;
    if (node < N) r = atomicAdd(&h[dc], 1);
    __syncthreads();
    int c0 = h[t];       if (c0) base[t]       = atomicAdd(&dstart[t], c0);
    int c1 = h[t + 256]; if (c1) base[t + 256] = atomicAdd(&dstart[t + 256], c1);
    __syncthreads();
    if (node < N) desc[base[dc] + r] = make_int4(node, rs, dv, 0);
}

// ---------------- split-bf16 MFMA GEMM ----------------
// out[N x MOUT] (per W-side) = A[N x 128] @ W.
// A@W ~= Ah@Wh + Ah@Wlo + Al@Wh  (lo*lo dropped, ~2^-18 relative).
// R12: blockIdx.y in {0,1} selects Wl vs Wr; each block computes ALL MOUT
// cols of its W (NT = MOUT/16 tiles in LDS). Previously 4 col-tile blocks
// re-read the same A rows (4x over-read, ~205MB/launch vs 25.6MB operand);
// now A is read once per W-side. LDS = 2*NT*4KB = 64KB at MOUT=128
// (static cap), 2 blocks/CU.
template<int MOUT, bool CONVA>
__global__ __launch_bounds__(256) void gemm_mfma(const ushort_t* __restrict__ Ah,
                                                 const ushort_t* __restrict__ Al,
                                                 const float* __restrict__ Af,
                                                 const float* __restrict__ Wl,
                                                 const float* __restrict__ Wr,
                                                 ushort_t* __restrict__ xlh,
                                                 ushort_t* __restrict__ xrh, int N) {
    constexpr int NT  = MOUT / 16;      // 16-col tiles: 8 (MOUT=128) / 4 (64)
    constexpr int FPT = MOUT / 8;       // float4 loads per thread
    constexpr int CPR = MOUT / 4;       // float4 columns per k-row
    __shared__ __align__(16) ushort_t Bh[NT * 2048];   // NT*4KB
    __shared__ __align__(16) ushort_t Bl[NT * 2048];
    const int tid   = threadIdx.x;
    const int row0  = blockIdx.x * 128;
    const bool isR  = blockIdx.y != 0;
    const float* W  = isR ? Wr : Wl;
    ushort_t* OUT   = isR ? xrh : xlh;

    #pragma unroll
    for (int i = 0; i < FPT; ++i) {
        int idx = tid * FPT + i;
        int k   = idx / CPR;
        int c4  = (idx % CPR) * 4;
        float4 w = *(const float4*)(W + (size_t)k * MOUT + c4);
        float wv[4] = {w.x, w.y, w.z, w.w};
        int q = k >> 5, quad = (k >> 3) & 3, j = k & 7;
        #pragma unroll
        for (int e = 0; e < 4; ++e) {
            int c = c4 + e;
            int t = c >> 4;
            int l = (quad << 4) | (c & 15);
            int pos = ((t * 4 + q) * 64 + l) * 8 + j;
            ushort_t hb = f2bf(wv[e]);
            Bh[pos] = hb;
            Bl[pos] = f2bf(wv[e] - bf2f(hb));
        }
    }
    __syncthreads();

    const int wv_  = tid >> 6;
    const int lane = tid & 63;
    const int m    = lane & 15;
    const int quad = lane >> 4;
    const int wrow0 = row0 + wv_ * 32;

    f32x4 acc[2][NT] = {};

    for (int q = 0; q < 4; ++q) {
        short8 ahf[2], alf[2];
        #pragma unroll
        for (int r = 0; r < 2; ++r) {
            int row = wrow0 + 16 * r + m;
            row = row < N ? row : N - 1;
            size_t off = (size_t)row * 128 + q * 32 + quad * 8;
            if constexpr (CONVA) {
                float4 f0 = *(const float4*)(Af + off);
                float4 f1 = *(const float4*)(Af + off + 4);
                float fv[8] = {f0.x, f0.y, f0.z, f0.w, f1.x, f1.y, f1.z, f1.w};
                short ah[8], al[8];
                #pragma unroll
                for (int e = 0; e < 8; ++e) {
                    ushort_t hb = f2bf(fv[e]);
                    ah[e] = (short)hb;
                    al[e] = (short)f2bf(fv[e] - bf2f(hb));
                }
                ahf[r] = short8{ah[0],ah[1],ah[2],ah[3],ah[4],ah[5],ah[6],ah[7]};
                alf[r] = short8{al[0],al[1],al[2],al[3],al[4],al[5],al[6],al[7]};
            } else {
                ahf[r] = *(const short8*)(Ah + off);
                alf[r] = *(const short8*)(Al + off);
            }
        }
        #pragma unroll
        for (int t = 0; t < NT; ++t) {
            int base = ((t * 4 + q) * 64 + lane) * 8;
            short8 bh = *(const short8*)(Bh + base);
            short8 bl = *(const short8*)(Bl + base);
            #pragma unroll
            for (int r = 0; r < 2; ++r) {
                acc[r][t] = __builtin_amdgcn_mfma_f32_16x16x32_bf16(ahf[r], bh, acc[r][t], 0, 0, 0);
                acc[r][t] = __builtin_amdgcn_mfma_f32_16x16x32_bf16(ahf[r], bl, acc[r][t], 0, 0, 0);
                acc[r][t] = __builtin_amdgcn_mfma_f32_16x16x32_bf16(alf[r], bh, acc[r][t], 0, 0, 0);
            }
        }
    }

    #pragma unroll
    for (int r = 0; r < 2; ++r)
        #pragma unroll
        for (int i = 0; i < 4; ++i) {
            int row = wrow0 + 16 * r + quad * 4 + i;
            if (row < N) {
                #pragma unroll
                for (int t = 0; t < NT; ++t)
                    OUT[(size_t)row * MOUT + t * 16 + m] = f2h(acc[r][t][i]);
            }
        }
}

// ---------------- fused per-node attention: one 16-lane group per node ----------------
// R12 = R10's exact best config (DR=5). R11's DR=10 regressed (−13us:
// longer predicated tail + 2x inlined body + prologue over-fetch), so DR=5
// stands as the measured optimum of {5,10}. desc (packed {node,rowstart,deg})
// keeps setup at one 16B load.
template<int H, int C, bool ELU, int OMODE>
__global__ __launch_bounds__(512) void node_attn(const ushort_t* __restrict__ xlh,
                                                 const ushort_t* __restrict__ xrh,
                                                 const float* __restrict__ att,
                                                 const float* __restrict__ bias,
                                                 const int4* __restrict__ desc,
                                                 const int* __restrict__ csr_src,
                                                 int N, float* __restrict__ out,
                                                 ushort_t* __restrict__ outh,
                                                 ushort_t* __restrict__ outl) {
    constexpr int HC  = H * C;          // 128 / 64
    constexpr int VPT = 8;
    constexpr int LPG = HC / VPT;       // lanes per group: 16 / 8
    constexpr int GPW = 64 / LPG;       // groups (nodes) per wave: 4 / 8
    constexpr int GROUP = C / VPT;      // lanes per head: 4 / 8
    constexpr int DR  = 5;              // gather ring depth per group

    const int lane = threadIdx.x & 63;
    const int wv   = threadIdx.x >> 6;
    const int gid  = lane / LPG;
    const int lig  = lane % LPG;
    const int ch0  = lig * VPT;

    const int s = (blockIdx.x * 8 + wv) * GPW + gid;
    if (s >= N) return;

    // per-kernel invariants
    half2_t a2[4];
    {
        float4 u0 = *(const float4*)(att + ch0);
        float4 u1 = *(const float4*)(att + ch0 + 4);
        a2[0] = half2_t{(_Float16)u0.x, (_Float16)u0.y};
        a2[1] = half2_t{(_Float16)u0.z, (_Float16)u0.w};
        a2[2] = half2_t{(_Float16)u1.x, (_Float16)u1.y};
        a2[3] = half2_t{(_Float16)u1.z, (_Float16)u1.w};
    }
    float bias8[VPT];
    {
        float4 b0 = *(const float4*)(bias + ch0);
        float4 b1 = *(const float4*)(bias + ch0 + 4);
        bias8[0]=b0.x; bias8[1]=b0.y; bias8[2]=b0.z; bias8[3]=b0.w;
        bias8[4]=b1.x; bias8[5]=b1.y; bias8[6]=b1.z; bias8[7]=b1.w;
    }
    const half2_t c02 = half2_t{(_Float16)NEG_SLOPE, (_Float16)NEG_SLOPE};

    const int4 dsc = desc[s];
    const int n  = dsc.x;
    const int j0 = dsc.y;
    const int dg = dsc.z;               // >= 1 (self-loop)

    half8 xrv = *(const half8*)(xrh + (size_t)n * HC + ch0);

    auto ldidx = [&](int e) {
        int ee = e < dg ? e : dg - 1;   // clamp: harmless duplicate loads
        return csr_src[j0 + ee];
    };
    auto ldrow = [&](int idx) -> half8 {
        return *(const half8*)(xlh + (size_t)(unsigned)idx * HC + ch0);  // 16 B
    };

    float d = 0.f;
    float acc[VPT] = {};

    auto process = [&](half8 v) {
        float p = 0.f;
        #pragma unroll
        for (int i = 0; i < 4; ++i) {
            half2_t v2 = half2_t{v[2 * i], v[2 * i + 1]};
            half2_t x2 = half2_t{xrv[2 * i], xrv[2 * i + 1]};
            half2_t m2 = v2 + x2;                                 // v_pk_add_f16
            half2_t lr = __builtin_elementwise_max(m2, c02 * m2); // pk_mul+pk_max
            p = dot2acc(lr, a2[i], p);                            // v_dot2_f32_f16
        }
        // head reduce: quad DPP (lanes of one head are an aligned quad),
        // plus lane^4 swizzle when the head spans 8 lanes (layer 3).
        if constexpr (GROUP >= 2) p = dpp_add<0xB1>(p);  // xor 1
        if constexpr (GROUP >= 4) p = dpp_add<0x4E>(p);  // xor 2
        if constexpr (GROUP >= 8) p = swz4_add(p);       // xor 4
        float pe = __expf(p);
        d += pe;
        #pragma unroll
        for (int i = 0; i < VPT; ++i)
            acc[i] += pe * (float)v[i];                           // fma_mix-able
    };

    // ring prologue: indices, then rows (+ next indices)
    int   ibuf[DR];
    half8 rbuf[DR];
    #pragma unroll
    for (int k = 0; k < DR; ++k) ibuf[k] = ldidx(k);
    #pragma unroll
    for (int k = 0; k < DR; ++k) {
        rbuf[k] = ldrow(ibuf[k]);
        ibuf[k] = ldidx(k + DR);
    }

    int e = 0;
    for (; e + DR <= dg; e += DR) {      // group-uniform trip count
        #pragma unroll
        for (int k = 0; k < DR; ++k) {
            half8 v = rbuf[k];
            rbuf[k] = ldrow(ibuf[k]);
            ibuf[k] = ldidx(e + k + 2 * DR);
            process(v);
        }
    }
    #pragma unroll
    for (int k = 0; k < DR; ++k)
        if (e + k < dg) process(rbuf[k]);

    // epilogue: d and acc are lane-local (d uniform across the head's lanes)
    float inv = 1.f / d;
    float vv[VPT];
    #pragma unroll
    for (int i = 0; i < VPT; ++i) {
        float v = acc[i] * inv + bias8[i];
        if (ELU) v = v > 0.f ? v : (__expf(v) - 1.f);
        vv[i] = v;
    }
    if (OMODE == 0) {
        *(float4*)(out + (size_t)n * HC + ch0) =
            make_float4(vv[0], vv[1], vv[2], vv[3]);
        *(float4*)(out + (size_t)n * HC + ch0 + 4) =
            make_float4(vv[4], vv[5], vv[6], vv[7]);
    } else {
        ushort_t hb[VPT], lb[VPT];
        #pragma unroll
        for (int i = 0; i < VPT; ++i) {
            hb[i] = f2bf(vv[i]);
            lb[i] = f2bf(vv[i] - bf2f(hb[i]));
        }
        *(ushort4*)(outh + (size_t)n * HC + ch0) =
            ushort4{hb[0], hb[1], hb[2], hb[3]};
        *(ushort4*)(outh + (size_t)n * HC + ch0 + 4) =
            ushort4{hb[4], hb[5], hb[6], hb[7]};
        *(ushort4*)(outl + (size_t)n * HC + ch0) =
            ushort4{lb[0], lb[1], lb[2], lb[3]};
        *(ushort4*)(outl + (size_t)n * HC + ch0 + 4) =
            ushort4{lb[4], lb[5], lb[6], lb[7]};
    }
}

// ---------------- launch ----------------
extern "C" void kernel_launch(void* const* d_in, const int* in_sizes, int n_in,
                              void* d_out, int out_size, void* d_ws, size_t ws_size,
                              hipStream_t stream) {
    const float* x   = (const float*)d_in[0];
    const int*   ei  = (const int*)d_in[1];
    const float* Wl1 = (const float*)d_in[2];
    const float* Wr1 = (const float*)d_in[3];
    const float* a1  = (const float*)d_in[4];
    const float* b1  = (const float*)d_in[5];
    const float* Wl2 = (const float*)d_in[6];
    const float* Wr2 = (const float*)d_in[7];
    const float* a2  = (const float*)d_in[8];
    const float* b2  = (const float*)d_in[9];
    const float* Wl3 = (const float*)d_in[10];
    const float* Wr3 = (const float*)d_in[11];
    const float* a3  = (const float*)d_in[12];
    const float* b3  = (const float*)d_in[13];

    const int N  = in_sizes[0] / 128;   // 50000
    const int E  = in_sizes[1] / 2;     // 800000
    const int Et = E + N;               // 850000
    const int nb = (N + 255) / 256;     // 196 (= bucket count)

    char* p = (char*)d_ws;
    auto alloc = [&](size_t bytes) -> void* {
        void* r = (void*)p;
        p += (bytes + 255) & ~(size_t)255;
        return r;
    };
    const int ebBlocks = (Et + EB - 1) / EB;    // 208
    int*      csr_src  = (int*)alloc((size_t)Et * 4 + 256);
    unsigned* ebuf     = (unsigned*)alloc((size_t)Et * 4);
    int*      blkcnt   = (int*)alloc((size_t)ebBlocks * 256 * 4);
    int*      btot     = (int*)alloc(256 * 4);
    int*      bbase    = (int*)alloc(256 * 4);
    int*      deg      = (int*)alloc((size_t)N * 4);
    int*      rowstart = (int*)alloc((size_t)N * 4);
    int*      partials = (int*)alloc((size_t)nb * 4);
    int4*     desc     = (int4*)alloc((size_t)N * 16);
    int*      dhist    = (int*)alloc((size_t)DEGB * 4);
    int*      dstart   = (int*)alloc((size_t)DEGB * 4);
    ushort_t* xlh      = (ushort_t*)alloc((size_t)N * 128 * 2);  // fp16 gather table
    ushort_t* xrh      = (ushort_t*)alloc((size_t)N * 128 * 2);  // fp16 target table
    ushort_t* Ah       = (ushort_t*)alloc((size_t)N * 128 * 2);
    ushort_t* Al       = (ushort_t*)alloc((size_t)N * 128 * 2);

    const int rowBlocks    = (N + 127) / 128;   // 391
    const int nodeBlocks12 = (N + 31) / 32;     // 1 node per 16-lane group
    const int nodeBlocks3  = (N + 63) / 64;     // 1 node per 8-lane group

    // ---- bucketed CSR by dst + degree-sorted node descriptors (once; reused) ----
    hipMemsetAsync(dhist, 0, (size_t)DEGB * 4, stream);
    bucket_hist<<<ebBlocks, 256, 0, stream>>>(ei, E, Et, blkcnt);
    colscan<<<256, 64, 0, stream>>>(blkcnt, ebBlocks, btot);
    bucketscan<<<1, 256, 0, stream>>>(btot, bbase);
    bucket_scatter<<<ebBlocks, 256, 0, stream>>>(ei, E, Et, blkcnt, bbase, ebuf);
    bucket_deg_scan_hist<<<nb, 256, 0, stream>>>(ebuf, bbase, btot, N,
                                                 deg, rowstart, partials, dhist);
    finalize_scans<<<nb + 1, DEGB, 0, stream>>>(rowstart, partials, nb, N,
                                                dhist, dstart);
    csr_perm_scatter<<<nb, 256, 0, stream>>>(ebuf, bbase, btot, rowstart, deg, N,
                                             dstart, csr_src, desc);

    // ---- layer 1: 128 -> 4x32, concat, ELU (A converted inline from f32) ----
    gemm_mfma<128, true><<<dim3(rowBlocks, 2), 256, 0, stream>>>(
        nullptr, nullptr, x, Wl1, Wr1, xlh, xrh, N);
    node_attn<4, 32, true, 1><<<nodeBlocks12, 512, 0, stream>>>(
        xlh, xrh, a1, b1, desc, csr_src, N, nullptr, Ah, Al);

    // ---- layer 2: 128 -> 4x32, concat, ELU ----
    gemm_mfma<128, false><<<dim3(rowBlocks, 2), 256, 0, stream>>>(
        Ah, Al, nullptr, Wl2, Wr2, xlh, xrh, N);
    node_attn<4, 32, true, 1><<<nodeBlocks12, 512, 0, stream>>>(
        xlh, xrh, a2, b2, desc, csr_src, N, nullptr, Ah, Al);

    // ---- layer 3: 128 -> 64, heads=1, concat=False ----
    float* out = (float*)d_out;
    gemm_mfma<64, false><<<dim3(rowBlocks, 2), 256, 0, stream>>>(
        Ah, Al, nullptr, Wl3, Wr3, xlh, xrh, N);
    node_attn<1, 64, false, 0><<<nodeBlocks3, 512, 0, stream>>>(
        xlh, xrh, a3, b3, desc, csr_src, N, out, nullptr, nullptr);
}

// Round 13
// 280.511 us; speedup vs baseline: 1.1074x; 1.0213x over previous
//
#include <hip/hip_runtime.h>
#include <cstdint>
#include <cstddef>
#include <math.h>

#define NEG_SLOPE 0.2f
#define DEGB 512
#define EB 4096            // edges per block in the bucketed CSR build

typedef unsigned short ushort_t;
typedef __attribute__((ext_vector_type(8))) short short8;      // bf16x8 MFMA operand
typedef __attribute__((ext_vector_type(4))) float f32x4;       // MFMA accumulator
typedef _Float16 half8 __attribute__((ext_vector_type(8)));    // fp16x8 row chunk
typedef _Float16 half2_t __attribute__((ext_vector_type(2)));  // fp16x2 packed

// f32 -> bf16 (RNE); bf16 -> f32 is shl 16.
__device__ __forceinline__ ushort_t f2bf(float f) {
    unsigned u = __float_as_uint(f);
    unsigned r = u + 0x7FFFu + ((u >> 16) & 1u);
    return (ushort_t)(r >> 16);
}
__device__ __forceinline__ float bf2f(ushort_t h) {
    return __uint_as_float(((unsigned)h) << 16);
}
__device__ __forceinline__ ushort_t f2h(float f) {
    _Float16 h = (_Float16)f;
    return *(ushort_t*)&h;
}

__device__ __forceinline__ float dot2acc(half2_t a, half2_t b, float c) {
#if __has_builtin(__builtin_amdgcn_fdot2)
    return __builtin_amdgcn_fdot2(a, b, c, false);
#else
    return c + (float)a[0] * (float)b[0] + (float)a[1] * (float)b[1];
#endif
}

// DPP quad butterfly add: p += lane[p ^ k] for k in {1,2} within each quad.
// quad_perm [1,0,3,2] = 0xB1 (xor1), [2,3,0,1] = 0x4E (xor2).
template<int CTRL>
__device__ __forceinline__ float dpp_add(float p) {
    int t = __builtin_amdgcn_update_dpp(0, __builtin_bit_cast(int, p),
                                        CTRL, 0xF, 0xF, true);
    return p + __builtin_bit_cast(float, t);
}

// lane^4 butterfly add via ds_swizzle (BitMode: xor_mask<<10 | and 0x1F)
__device__ __forceinline__ float swz4_add(float p) {
    int t = __builtin_amdgcn_ds_swizzle(__builtin_bit_cast(int, p), 0x101F);
    return p + __builtin_bit_cast(float, t);
}

__device__ __forceinline__ int wave_incl_scan(int v, int lane) {
    #pragma unroll
    for (int o = 1; o < 64; o <<= 1) {
        int t = __shfl_up(v, o, 64);
        if (lane >= o) v += t;
    }
    return v;
}

// ================= bucketed CSR build (fused stages) =================
// R13: bucket_hist is merged into the layer-1 gemm launch (independent work,
// hides ~10us + one dispatch gap); dhist zeroing folded into colscan.

// pass B1: for each bucket (column), exclusive scan over blocks; total -> btot.
// Also zeroes dhist (512 ints across 256 blocks) for the later histogram.
__global__ void colscan(int* __restrict__ blkcnt, int nblk, int* __restrict__ btot,
                        int* __restrict__ dhist) {
    int b = blockIdx.x;             // bucket 0..255
    int lane = threadIdx.x;         // 64 threads
    if (lane < 2) dhist[b * 2 + lane] = 0;
    int running = 0;
    for (int base = 0; base < nblk; base += 64) {
        int idx = base + lane;
        int v = (idx < nblk) ? blkcnt[idx * 256 + b] : 0;
        int incl = wave_incl_scan(v, lane);
        if (idx < nblk) blkcnt[idx * 256 + b] = running + incl - v;
        running += __shfl(incl, 63, 64);
    }
    if (lane == 0) btot[b] = running;
}

// pass B2: exclusive scan of bucket totals -> bucket bases
__global__ void bucketscan(const int* __restrict__ btot, int* __restrict__ bbase) {
    __shared__ int tmp[256];
    int t = threadIdx.x;
    int v = btot[t];
    tmp[t] = v;
    __syncthreads();
    for (int o = 1; o < 256; o <<= 1) {
        int x = (t >= o) ? tmp[t - o] : 0;
        __syncthreads();
        tmp[t] += x;
        __syncthreads();
    }
    bbase[t] = tmp[t] - v;
}

// pass C: scatter packed edges into bucket-grouped ebuf.
// pack = src | (dst&255)<<17  (valid: N=50000 < 2^17)
__global__ void bucket_scatter(const int* __restrict__ ei, int E, int Et,
                               const int* __restrict__ blkrel,
                               const int* __restrict__ bbase,
                               unsigned* __restrict__ ebuf) {
    __shared__ int base_l[256];
    __shared__ int cnt[256];
    int t = threadIdx.x;
    base_l[t] = bbase[t] + blkrel[blockIdx.x * 256 + t];
    cnt[t] = 0;
    __syncthreads();
    int e0 = blockIdx.x * EB;
    #pragma unroll
    for (int it = 0; it < EB / 256; ++it) {
        int e = e0 + it * 256 + t;
        if (e < Et) {
            int s, d;
            if (e < E) { s = ei[e]; d = ei[E + e]; }
            else       { s = d = e - E; }
            int b = d >> 8;
            int r = atomicAdd(&cnt[b], 1);
            ebuf[base_l[b] + r] = (unsigned)s | (((unsigned)d & 255u) << 17);
        }
    }
}

// pass D (fused csr_count + scan1 + deg_hist): per-bucket degree counts,
// block-local prefix (rowstart partial), degree histogram.
__global__ void bucket_deg_scan_hist(const unsigned* __restrict__ ebuf,
                                     const int* __restrict__ bbase,
                                     const int* __restrict__ btot,
                                     int N, int* __restrict__ deg,
                                     int* __restrict__ rowstart,
                                     int* __restrict__ partials,
                                     int* __restrict__ dhist) {
    __shared__ int dcnt[256];
    __shared__ int tmp[256];
    __shared__ int h[DEGB];
    int b = blockIdx.x, t = threadIdx.x;
    dcnt[t] = 0;
    h[t] = 0; h[t + 256] = 0;
    __syncthreads();
    int s0 = bbase[b], c = btot[b];
    for (int i = t; i < c; i += 256)
        atomicAdd(&dcnt[ebuf[s0 + i] >> 17], 1);
    __syncthreads();
    int node = b * 256 + t;
    int dv = dcnt[t];
    if (node < N) deg[node] = dv;
    tmp[t] = dv;
    __syncthreads();
    for (int o = 1; o < 256; o <<= 1) {
        int x = (t >= o) ? tmp[t - o] : 0;
        __syncthreads();
        tmp[t] += x;
        __syncthreads();
    }
    if (node < N) rowstart[node] = tmp[t] - dv;    // block-local exclusive
    if (t == 255) partials[b] = tmp[255];
    if (node < N) {
        int dc = dv < DEGB - 1 ? dv : DEGB - 1;
        atomicAdd(&h[dc], 1);
    }
    __syncthreads();
    int c0 = h[t];       if (c0) atomicAdd(&dhist[t], c0);
    int c1 = h[t + 256]; if (c1) atomicAdd(&dhist[t + 256], c1);
}

// pass E (fused scan23 + deg_scan): blocks 0..nbkt-1 finalize rowstart;
// block nbkt scans the 512-bin degree histogram -> descending dstart.
__global__ void finalize_scans(int* __restrict__ rowstart,
                               const int* __restrict__ partials, int nbkt, int N,
                               const int* __restrict__ dhist,
                               int* __restrict__ dstart) {
    __shared__ int tmp[DEGB];       // 512
    int t = threadIdx.x;            // 512 threads
    int b = blockIdx.x;
    if (b < nbkt) {
        if (t < 256) tmp[t] = (t < nbkt) ? partials[t] : 0;
        __syncthreads();
        for (int o = 1; o < 256; o <<= 1) {
            int x = (t < 256 && t >= o) ? tmp[t - o] : 0;
            __syncthreads();
            if (t < 256) tmp[t] += x;
            __syncthreads();
        }
        int off = (b > 0) ? tmp[b - 1] : 0;
        int node = b * 256 + t;
        if (t < 256 && node < N) rowstart[node] += off;
    } else {
        int v = dhist[t];
        tmp[t] = v;
        __syncthreads();
        for (int o = 1; o < DEGB; o <<= 1) {
            int x = (t >= o) ? tmp[t - o] : 0;
            __syncthreads();
            tmp[t] += x;
            __syncthreads();
        }
        dstart[t] = tmp[DEGB - 1] - tmp[t];
    }
}

// pass F (fused csr_scatter2 + deg_scatter): CSR scatter with LDS cursors +
// degree-sorted 16B descriptor {node, rowstart, deg} scatter.
__global__ void csr_perm_scatter(const unsigned* __restrict__ ebuf,
                                 const int* __restrict__ bbase,
                                 const int* __restrict__ btot,
                                 const int* __restrict__ rowstart,
                                 const int* __restrict__ deg, int N,
                                 int* __restrict__ dstart,
                                 int* __restrict__ csr_src,
                                 int4* __restrict__ desc) {
    __shared__ int cur[256];
    __shared__ int h[DEGB];
    __shared__ int base[DEGB];
    int b = blockIdx.x, t = threadIdx.x;
    int node = b * 256 + t;
    int rs = (node < N) ? rowstart[node] : 0;
    cur[t] = rs;
    h[t] = 0; h[t + 256] = 0;
    __syncthreads();
    int s0 = bbase[b], c = btot[b];
    for (int i = t; i < c; i += 256) {
        unsigned v = ebuf[s0 + i];
        int pos = atomicAdd(&cur[v >> 17], 1);
        csr_src[pos] = (int)(v & 0x1FFFFu);
    }
    int dv = (node < N) ? deg[node] : 0;
    int dc = dv < DEGB - 1 ? dv : DEGB - 1;
    int r = 0;
    if (node < N) r = atomicAdd(&h[dc], 1);
    __syncthreads();
    int c0 = h[t];       if (c0) base[t]       = atomicAdd(&dstart[t], c0);
    int c1 = h[t + 256]; if (c1) base[t + 256] = atomicAdd(&dstart[t + 256], c1);
    __syncthreads();
    if (node < N) desc[base[dc] + r] = make_int4(node, rs, dv, 0);
}

// ---------------- split-bf16 MFMA GEMM (+ optional fused bucket_hist) ----------------
// out[N x MOUT] (per W-side) = A[N x 128] @ W.
// A@W ~= Ah@Wh + Ah@Wlo + Al@Wh  (lo*lo dropped, ~2^-18 relative).
// blockIdx decodes: first histBlocks blocks run the CSR bucket histogram
// (independent work, hidden under the gemm — R13); the rest do the gemm with
// g = blockIdx.x - histBlocks, row tile g>>1, W-side g&1. Each block computes
// ALL MOUT cols of its W (A read once per W-side; R12). Hist's 1KB LDS
// aliases into Bh (roles are mutually exclusive) to stay at the 64KB cap.
template<int MOUT, bool CONVA>
__global__ __launch_bounds__(256) void gemm_mfma(const ushort_t* __restrict__ Ah,
                                                 const ushort_t* __restrict__ Al,
                                                 const float* __restrict__ Af,
                                                 const float* __restrict__ Wl,
                                                 const float* __restrict__ Wr,
                                                 ushort_t* __restrict__ xlh,
                                                 ushort_t* __restrict__ xrh, int N,
                                                 const int* __restrict__ ei,
                                                 int E, int Et,
                                                 int* __restrict__ blkcnt,
                                                 int histBlocks) {
    constexpr int NT  = MOUT / 16;      // 16-col tiles: 8 (MOUT=128) / 4 (64)
    constexpr int FPT = MOUT / 8;       // float4 loads per thread
    constexpr int CPR = MOUT / 4;       // float4 columns per k-row
    __shared__ __align__(16) ushort_t Bh[NT * 2048];   // NT*4KB
    __shared__ __align__(16) ushort_t Bl[NT * 2048];
    const int tid = threadIdx.x;

    if ((int)blockIdx.x < histBlocks) {
        // ---- fused bucket_hist: 256-bin histogram of dst>>8 per 4096 edges ----
        int* cnt = (int*)Bh;            // alias: hist blocks never run the gemm
        cnt[tid] = 0;
        __syncthreads();
        int e0 = blockIdx.x * EB;
        #pragma unroll
        for (int it = 0; it < EB / 256; ++it) {
            int e = e0 + it * 256 + tid;
            if (e < Et) {
                int d = (e < E) ? ei[E + e] : (e - E);
                atomicAdd(&cnt[d >> 8], 1);
            }
        }
        __syncthreads();
        blkcnt[blockIdx.x * 256 + tid] = cnt[tid];
        return;
    }

    const int g     = (int)blockIdx.x - histBlocks;
    const int row0  = (g >> 1) * 128;
    const bool isR  = (g & 1) != 0;
    const float* W  = isR ? Wr : Wl;
    ushort_t* OUT   = isR ? xrh : xlh;

    #pragma unroll
    for (int i = 0; i < FPT; ++i) {
        int idx = tid * FPT + i;
        int k   = idx / CPR;
        int c4  = (idx % CPR) * 4;
        float4 w = *(const float4*)(W + (size_t)k * MOUT + c4);
        float wv[4] = {w.x, w.y, w.z, w.w};
        int q = k >> 5, quad = (k >> 3) & 3, j = k & 7;
        #pragma unroll
        for (int e = 0; e < 4; ++e) {
            int c = c4 + e;
            int t = c >> 4;
            int l = (quad << 4) | (c & 15);
            int pos = ((t * 4 + q) * 64 + l) * 8 + j;
            ushort_t hb = f2bf(wv[e]);
            Bh[pos] = hb;
            Bl[pos] = f2bf(wv[e] - bf2f(hb));
        }
    }
    __syncthreads();

    const int wv_  = tid >> 6;
    const int lane = tid & 63;
    const int m    = lane & 15;
    const int quad = lane >> 4;
    const int wrow0 = row0 + wv_ * 32;

    f32x4 acc[2][NT] = {};

    for (int q = 0; q < 4; ++q) {
        short8 ahf[2], alf[2];
        #pragma unroll
        for (int r = 0; r < 2; ++r) {
            int row = wrow0 + 16 * r + m;
            row = row < N ? row : N - 1;
            size_t off = (size_t)row * 128 + q * 32 + quad * 8;
            if constexpr (CONVA) {
                float4 f0 = *(const float4*)(Af + off);
                float4 f1 = *(const float4*)(Af + off + 4);
                float fv[8] = {f0.x, f0.y, f0.z, f0.w, f1.x, f1.y, f1.z, f1.w};
                short ah[8], al[8];
                #pragma unroll
                for (int e = 0; e < 8; ++e) {
                    ushort_t hb = f2bf(fv[e]);
                    ah[e] = (short)hb;
                    al[e] = (short)f2bf(fv[e] - bf2f(hb));
                }
                ahf[r] = short8{ah[0],ah[1],ah[2],ah[3],ah[4],ah[5],ah[6],ah[7]};
                alf[r] = short8{al[0],al[1],al[2],al[3],al[4],al[5],al[6],al[7]};
            } else {
                ahf[r] = *(const short8*)(Ah + off);
                alf[r] = *(const short8*)(Al + off);
            }
        }
        #pragma unroll
        for (int t = 0; t < NT; ++t) {
            int base = ((t * 4 + q) * 64 + lane) * 8;
            short8 bh = *(const short8*)(Bh + base);
            short8 bl = *(const short8*)(Bl + base);
            #pragma unroll
            for (int r = 0; r < 2; ++r) {
                acc[r][t] = __builtin_amdgcn_mfma_f32_16x16x32_bf16(ahf[r], bh, acc[r][t], 0, 0, 0);
                acc[r][t] = __builtin_amdgcn_mfma_f32_16x16x32_bf16(ahf[r], bl, acc[r][t], 0, 0, 0);
                acc[r][t] = __builtin_amdgcn_mfma_f32_16x16x32_bf16(alf[r], bh, acc[r][t], 0, 0, 0);
            }
        }
    }

    #pragma unroll
    for (int r = 0; r < 2; ++r)
        #pragma unroll
        for (int i = 0; i < 4; ++i) {
            int row = wrow0 + 16 * r + quad * 4 + i;
            if (row < N) {
                #pragma unroll
                for (int t = 0; t < NT; ++t)
                    OUT[(size_t)row * MOUT + t * 16 + m] = f2h(acc[r][t][i]);
            }
        }
}

// ---------------- fused per-node attention: one 16-lane group per node ----------------
// Best-known config (R10/R12): DR=5 (R11's DR=10 regressed), 1 node per
// group, full grid (R9's 2-node pipelining regressed), desc packed
// {node,rowstart,deg} setup = one 16B load.
template<int H, int C, bool ELU, int OMODE>
__global__ __launch_bounds__(512) void node_attn(const ushort_t* __restrict__ xlh,
                                                 const ushort_t* __restrict__ xrh,
                                                 const float* __restrict__ att,
                                                 const float* __restrict__ bias,
                                                 const int4* __restrict__ desc,
                                                 const int* __restrict__ csr_src,
                                                 int N, float* __restrict__ out,
                                                 ushort_t* __restrict__ outh,
                                                 ushort_t* __restrict__ outl) {
    constexpr int HC  = H * C;          // 128 / 64
    constexpr int VPT = 8;
    constexpr int LPG = HC / VPT;       // lanes per group: 16 / 8
    constexpr int GPW = 64 / LPG;       // groups (nodes) per wave: 4 / 8
    constexpr int GROUP = C / VPT;      // lanes per head: 4 / 8
    constexpr int DR  = 5;              // gather ring depth per group

    const int lane = threadIdx.x & 63;
    const int wv   = threadIdx.x >> 6;
    const int gid  = lane / LPG;
    const int lig  = lane % LPG;
    const int ch0  = lig * VPT;

    const int s = (blockIdx.x * 8 + wv) * GPW + gid;
    if (s >= N) return;

    // per-kernel invariants
    half2_t a2[4];
    {
        float4 u0 = *(const float4*)(att + ch0);
        float4 u1 = *(const float4*)(att + ch0 + 4);
        a2[0] = half2_t{(_Float16)u0.x, (_Float16)u0.y};
        a2[1] = half2_t{(_Float16)u0.z, (_Float16)u0.w};
        a2[2] = half2_t{(_Float16)u1.x, (_Float16)u1.y};
        a2[3] = half2_t{(_Float16)u1.z, (_Float16)u1.w};
    }
    float bias8[VPT];
    {
        float4 b0 = *(const float4*)(bias + ch0);
        float4 b1 = *(const float4*)(bias + ch0 + 4);
        bias8[0]=b0.x; bias8[1]=b0.y; bias8[2]=b0.z; bias8[3]=b0.w;
        bias8[4]=b1.x; bias8[5]=b1.y; bias8[6]=b1.z; bias8[7]=b1.w;
    }
    const half2_t c02 = half2_t{(_Float16)NEG_SLOPE, (_Float16)NEG_SLOPE};

    const int4 dsc = desc[s];
    const int n  = dsc.x;
    const int j0 = dsc.y;
    const int dg = dsc.z;               // >= 1 (self-loop)

    half8 xrv = *(const half8*)(xrh + (size_t)n * HC + ch0);

    auto ldidx = [&](int e) {
        int ee = e < dg ? e : dg - 1;   // clamp: harmless duplicate loads
        return csr_src[j0 + ee];
    };
    auto ldrow = [&](int idx) -> half8 {
        return *(const half8*)(xlh + (size_t)(unsigned)idx * HC + ch0);  // 16 B
    };

    float d = 0.f;
    float acc[VPT] = {};

    auto process = [&](half8 v) {
        float p = 0.f;
        #pragma unroll
        for (int i = 0; i < 4; ++i) {
            half2_t v2 = half2_t{v[2 * i], v[2 * i + 1]};
            half2_t x2 = half2_t{xrv[2 * i], xrv[2 * i + 1]};
            half2_t m2 = v2 + x2;                                 // v_pk_add_f16
            half2_t lr = __builtin_elementwise_max(m2, c02 * m2); // pk_mul+pk_max
            p = dot2acc(lr, a2[i], p);                            // v_dot2_f32_f16
        }
        // head reduce: quad DPP (lanes of one head are an aligned quad),
        // plus lane^4 swizzle when the head spans 8 lanes (layer 3).
        if constexpr (GROUP >= 2) p = dpp_add<0xB1>(p);  // xor 1
        if constexpr (GROUP >= 4) p = dpp_add<0x4E>(p);  // xor 2
        if constexpr (GROUP >= 8) p = swz4_add(p);       // xor 4
        float pe = __expf(p);
        d += pe;
        #pragma unroll
        for (int i = 0; i < VPT; ++i)
            acc[i] += pe * (float)v[i];                           // fma_mix-able
    };

    // ring prologue: indices, then rows (+ next indices)
    int   ibuf[DR];
    half8 rbuf[DR];
    #pragma unroll
    for (int k = 0; k < DR; ++k) ibuf[k] = ldidx(k);
    #pragma unroll
    for (int k = 0; k < DR; ++k) {
        rbuf[k] = ldrow(ibuf[k]);
        ibuf[k] = ldidx(k + DR);
    }

    int e = 0;
    for (; e + DR <= dg; e += DR) {      // group-uniform trip count
        #pragma unroll
        for (int k = 0; k < DR; ++k) {
            half8 v = rbuf[k];
            rbuf[k] = ldrow(ibuf[k]);
            ibuf[k] = ldidx(e + k + 2 * DR);
            process(v);
        }
    }
    #pragma unroll
    for (int k = 0; k < DR; ++k)
        if (e + k < dg) process(rbuf[k]);

    // epilogue: d and acc are lane-local (d uniform across the head's lanes)
    float inv = 1.f / d;
    float vv[VPT];
    #pragma unroll
    for (int i = 0; i < VPT; ++i) {
        float v = acc[i] * inv + bias8[i];
        if (ELU) v = v > 0.f ? v : (__expf(v) - 1.f);
        vv[i] = v;
    }
    if (OMODE == 0) {
        *(float4*)(out + (size_t)n * HC + ch0) =
            make_float4(vv[0], vv[1], vv[2], vv[3]);
        *(float4*)(out + (size_t)n * HC + ch0 + 4) =
            make_float4(vv[4], vv[5], vv[6], vv[7]);
    } else {
        ushort_t hb[VPT], lb[VPT];
        #pragma unroll
        for (int i = 0; i < VPT; ++i) {
            hb[i] = f2bf(vv[i]);
            lb[i] = f2bf(vv[i] - bf2f(hb[i]));
        }
        *(ushort4*)(outh + (size_t)n * HC + ch0) =
            ushort4{hb[0], hb[1], hb[2], hb[3]};
        *(ushort4*)(outh + (size_t)n * HC + ch0 + 4) =
            ushort4{hb[4], hb[5], hb[6], hb[7]};
        *(ushort4*)(outl + (size_t)n * HC + ch0) =
            ushort4{lb[0], lb[1], lb[2], lb[3]};
        *(ushort4*)(outl + (size_t)n * HC + ch0 + 4) =
            ushort4{lb[4], lb[5], lb[6], lb[7]};
    }
}

// ---------------- launch ----------------
extern "C" void kernel_launch(void* const* d_in, const int* in_sizes, int n_in,
                              void* d_out, int out_size, void* d_ws, size_t ws_size,
                              hipStream_t stream) {
    const float* x   = (const float*)d_in[0];
    const int*   ei  = (const int*)d_in[1];
    const float* Wl1 = (const float*)d_in[2];
    const float* Wr1 = (const float*)d_in[3];
    const float* a1  = (const float*)d_in[4];
    const float* b1  = (const float*)d_in[5];
    const float* Wl2 = (const float*)d_in[6];
    const float* Wr2 = (const float*)d_in[7];
    const float* a2  = (const float*)d_in[8];
    const float* b2  = (const float*)d_in[9];
    const float* Wl3 = (const float*)d_in[10];
    const float* Wr3 = (const float*)d_in[11];
    const float* a3  = (const float*)d_in[12];
    const float* b3  = (const float*)d_in[13];

    const int N  = in_sizes[0] / 128;   // 50000
    const int E  = in_sizes[1] / 2;     // 800000
    const int Et = E + N;               // 850000
    const int nb = (N + 255) / 256;     // 196 (= bucket count)

    char* p = (char*)d_ws;
    auto alloc = [&](size_t bytes) -> void* {
        void* r = (void*)p;
        p += (bytes + 255) & ~(size_t)255;
        return r;
    };
    const int ebBlocks = (Et + EB - 1) / EB;    // 208
    int*      csr_src  = (int*)alloc((size_t)Et * 4 + 256);
    unsigned* ebuf     = (unsigned*)alloc((size_t)Et * 4);
    int*      blkcnt   = (int*)alloc((size_t)ebBlocks * 256 * 4);
    int*      btot     = (int*)alloc(256 * 4);
    int*      bbase    = (int*)alloc(256 * 4);
    int*      deg      = (int*)alloc((size_t)N * 4);
    int*      rowstart = (int*)alloc((size_t)N * 4);
    int*      partials = (int*)alloc((size_t)nb * 4);
    int4*     desc     = (int4*)alloc((size_t)N * 16);
    int*      dhist    = (int*)alloc((size_t)DEGB * 4);
    int*      dstart   = (int*)alloc((size_t)DEGB * 4);
    ushort_t* xlh      = (ushort_t*)alloc((size_t)N * 128 * 2);  // fp16 gather table
    ushort_t* xrh      = (ushort_t*)alloc((size_t)N * 128 * 2);  // fp16 target table
    ushort_t* Ah       = (ushort_t*)alloc((size_t)N * 128 * 2);
    ushort_t* Al       = (ushort_t*)alloc((size_t)N * 128 * 2);

    const int rowBlocks    = (N + 127) / 128;   // 391
    const int nodeBlocks12 = (N + 31) / 32;     // 1 node per 16-lane group
    const int nodeBlocks3  = (N + 63) / 64;     // 1 node per 8-lane group

    // ---- layer-1 gemm + fused CSR bucket histogram (independent work) ----
    gemm_mfma<128, true><<<ebBlocks + rowBlocks * 2, 256, 0, stream>>>(
        nullptr, nullptr, x, Wl1, Wr1, xlh, xrh, N, ei, E, Et, blkcnt, ebBlocks);

    // ---- rest of the bucketed CSR build (reused by all layers) ----
    colscan<<<256, 64, 0, stream>>>(blkcnt, ebBlocks, btot, dhist);
    bucketscan<<<1, 256, 0, stream>>>(btot, bbase);
    bucket_scatter<<<ebBlocks, 256, 0, stream>>>(ei, E, Et, blkcnt, bbase, ebuf);
    bucket_deg_scan_hist<<<nb, 256, 0, stream>>>(ebuf, bbase, btot, N,
                                                 deg, rowstart, partials, dhist);
    finalize_scans<<<nb + 1, DEGB, 0, stream>>>(rowstart, partials, nb, N,
                                                dhist, dstart);
    csr_perm_scatter<<<nb, 256, 0, stream>>>(ebuf, bbase, btot, rowstart, deg, N,
                                             dstart, csr_src, desc);

    // ---- layer 1 attention ----
    node_attn<4, 32, true, 1><<<nodeBlocks12, 512, 0, stream>>>(
        xlh, xrh, a1, b1, desc, csr_src, N, nullptr, Ah, Al);

    // ---- layer 2: 128 -> 4x32, concat, ELU ----
    gemm_mfma<128, false><<<rowBlocks * 2, 256, 0, stream>>>(
        Ah, Al, nullptr, Wl2, Wr2, xlh, xrh, N, nullptr, 0, 0, nullptr, 0);
    node_attn<4, 32, true, 1><<<nodeBlocks12, 512, 0, stream>>>(
        xlh, xrh, a2, b2, desc, csr_src, N, nullptr, Ah, Al);

    // ---- layer 3: 128 -> 64, heads=1, concat=False ----
    float* out = (float*)d_out;
    gemm_mfma<64, false><<<rowBlocks * 2, 256, 0, stream>>>(
        Ah, Al, nullptr, Wl3, Wr3, xlh, xrh, N, nullptr, 0, 0, nullptr, 0);
    node_attn<1, 64, false, 0><<<nodeBlocks3, 512, 0, stream>>>(
        xlh, xrh, a3, b3, desc, csr_src, N, out, nullptr, nullptr);
}

// Round 14
// 276.009 us; speedup vs baseline: 1.1255x; 1.0163x over previous
//
#include <hip/hip_runtime.h>
#include <cstdint>
#include <cstddef>
#include <math.h>

#define NEG_SLOPE 0.2f
#define DEGB 512
#define EB 4096            // edges per block in the bucketed CSR build

typedef unsigned short ushort_t;
typedef __attribute__((ext_vector_type(8))) short short8;      // bf16x8 MFMA operand
typedef __attribute__((ext_vector_type(4))) float f32x4;       // MFMA accumulator
typedef _Float16 half8 __attribute__((ext_vector_type(8)));    // fp16x8 row chunk
typedef _Float16 half2_t __attribute__((ext_vector_type(2)));  // fp16x2 packed

// f32 -> bf16 (RNE); bf16 -> f32 is shl 16.
__device__ __forceinline__ ushort_t f2bf(float f) {
    unsigned u = __float_as_uint(f);
    unsigned r = u + 0x7FFFu + ((u >> 16) & 1u);
    return (ushort_t)(r >> 16);
}
__device__ __forceinline__ float bf2f(ushort_t h) {
    return __uint_as_float(((unsigned)h) << 16);
}
__device__ __forceinline__ ushort_t f2h(float f) {
    _Float16 h = (_Float16)f;
    return *(ushort_t*)&h;
}

__device__ __forceinline__ float dot2acc(half2_t a, half2_t b, float c) {
#if __has_builtin(__builtin_amdgcn_fdot2)
    return __builtin_amdgcn_fdot2(a, b, c, false);
#else
    return c + (float)a[0] * (float)b[0] + (float)a[1] * (float)b[1];
#endif
}

// DPP quad butterfly add: p += lane[p ^ k] for k in {1,2} within each quad.
// quad_perm [1,0,3,2] = 0xB1 (xor1), [2,3,0,1] = 0x4E (xor2).
template<int CTRL>
__device__ __forceinline__ float dpp_add(float p) {
    int t = __builtin_amdgcn_update_dpp(0, __builtin_bit_cast(int, p),
                                        CTRL, 0xF, 0xF, true);
    return p + __builtin_bit_cast(float, t);
}

// lane^4 butterfly add via ds_swizzle (BitMode: xor_mask<<10 | and 0x1F)
__device__ __forceinline__ float swz4_add(float p) {
    int t = __builtin_amdgcn_ds_swizzle(__builtin_bit_cast(int, p), 0x101F);
    return p + __builtin_bit_cast(float, t);
}

__device__ __forceinline__ int wave_incl_scan(int v, int lane) {
    #pragma unroll
    for (int o = 1; o < 64; o <<= 1) {
        int t = __shfl_up(v, o, 64);
        if (lane >= o) v += t;
    }
    return v;
}

// ================= bucketed CSR build (R14: 4 prep kernels) =================
// R14 removes bucketscan + finalize_scans by recomputing small scans
// block-locally in each consumer (1KB LDS reads — cheaper than a dispatch):
//  - bbase[]: full 256-scan of btot in bucket_scatter; single-b reduction in
//    bucket_deg_scan_hist / csr_perm_scatter.
//  - rowstart offset: reduction of partials[0..b-1] in csr_perm_scatter.
//  - dstart: per-block 512-scan of dhist + global zeroed cursor dcur[] for
//    cross-block reservation (dcur zeroed in colscan beside dhist).

// pass B1: for each bucket (column), exclusive scan over blocks; total -> btot.
// Also zeroes dhist + dcur (512 ints each across 256 blocks).
__global__ void colscan(int* __restrict__ blkcnt, int nblk, int* __restrict__ btot,
                        int* __restrict__ dhist, int* __restrict__ dcur) {
    int b = blockIdx.x;             // bucket 0..255
    int lane = threadIdx.x;         // 64 threads
    if (lane < 2) { dhist[b * 2 + lane] = 0; dcur[b * 2 + lane] = 0; }
    int running = 0;
    for (int base = 0; base < nblk; base += 64) {
        int idx = base + lane;
        int v = (idx < nblk) ? blkcnt[idx * 256 + b] : 0;
        int incl = wave_incl_scan(v, lane);
        if (idx < nblk) blkcnt[idx * 256 + b] = running + incl - v;
        running += __shfl(incl, 63, 64);
    }
    if (lane == 0) btot[b] = running;
}

// pass C: scatter packed edges into bucket-grouped ebuf.
// pack = src | (dst&255)<<17  (valid: N=50000 < 2^17)
// bbase computed in-block: exclusive 256-scan of btot.
__global__ void bucket_scatter(const int* __restrict__ ei, int E, int Et,
                               const int* __restrict__ blkrel,
                               const int* __restrict__ btot,
                               unsigned* __restrict__ ebuf) {
    __shared__ int base_l[256];
    __shared__ int tmp[256];
    __shared__ int cnt[256];
    int t = threadIdx.x;
    int v = btot[t];
    tmp[t] = v;
    cnt[t] = 0;
    __syncthreads();
    for (int o = 1; o < 256; o <<= 1) {
        int x = (t >= o) ? tmp[t - o] : 0;
        __syncthreads();
        tmp[t] += x;
        __syncthreads();
    }
    base_l[t] = (tmp[t] - v) + blkrel[blockIdx.x * 256 + t];
    __syncthreads();
    int e0 = blockIdx.x * EB;
    #pragma unroll
    for (int it = 0; it < EB / 256; ++it) {
        int e = e0 + it * 256 + t;
        if (e < Et) {
            int s, d;
            if (e < E) { s = ei[e]; d = ei[E + e]; }
            else       { s = d = e - E; }
            int b = d >> 8;
            int r = atomicAdd(&cnt[b], 1);
            ebuf[base_l[b] + r] = (unsigned)s | (((unsigned)d & 255u) << 17);
        }
    }
}

// pass D (fused csr_count + scan1 + deg_hist): per-bucket degree counts,
// block-local prefix (rowstart partial), degree histogram.
// bbase[b] computed in-block (reduction over btot[0..b-1]).
__global__ void bucket_deg_scan_hist(const unsigned* __restrict__ ebuf,
                                     const int* __restrict__ btot,
                                     int N, int* __restrict__ deg,
                                     int* __restrict__ rowstart,
                                     int* __restrict__ partials,
                                     int* __restrict__ dhist) {
    __shared__ int dcnt[256];
    __shared__ int tmp[256];
    __shared__ int h[DEGB];
    int b = blockIdx.x, t = threadIdx.x;
    dcnt[t] = 0;
    h[t] = 0; h[t + 256] = 0;
    tmp[t] = (t < b) ? btot[t] : 0;
    __syncthreads();
    #pragma unroll
    for (int o = 128; o > 0; o >>= 1) {
        if (t < o) tmp[t] += tmp[t + o];
        __syncthreads();
    }
    const int s0 = tmp[0];
    const int c  = btot[b];
    __syncthreads();
    for (int i = t; i < c; i += 256)
        atomicAdd(&dcnt[ebuf[s0 + i] >> 17], 1);
    __syncthreads();
    int node = b * 256 + t;
    int dv = dcnt[t];
    if (node < N) deg[node] = dv;
    tmp[t] = dv;
    __syncthreads();
    for (int o = 1; o < 256; o <<= 1) {
        int x = (t >= o) ? tmp[t - o] : 0;
        __syncthreads();
        tmp[t] += x;
        __syncthreads();
    }
    if (node < N) rowstart[node] = tmp[t] - dv;    // block-local exclusive
    if (t == 255) partials[b] = tmp[255];
    if (node < N) {
        int dc = dv < DEGB - 1 ? dv : DEGB - 1;
        atomicAdd(&h[dc], 1);
    }
    __syncthreads();
    int c0 = h[t];       if (c0) atomicAdd(&dhist[t], c0);
    int c1 = h[t + 256]; if (c1) atomicAdd(&dhist[t + 256], c1);
}

// pass F (fused csr_scatter + perm/desc scatter; R14: also absorbs
// finalize_scans): CSR scatter with LDS cursors seeded from globally-offset
// rowstart (offset = in-block reduction of partials); degree-sorted 16B
// descriptor {node, global rowstart, deg} scatter with dstart computed from a
// per-block 512-scan of dhist + global cursor dcur reservation.
__global__ void csr_perm_scatter(const unsigned* __restrict__ ebuf,
                                 const int* __restrict__ btot,
                                 const int* __restrict__ rowstart,
                                 const int* __restrict__ partials,
                                 const int* __restrict__ deg, int N,
                                 const int* __restrict__ dhist,
                                 int* __restrict__ dcur,
                                 int* __restrict__ csr_src,
                                 int4* __restrict__ desc) {
    __shared__ int cur[256];
    __shared__ int tmp[256];
    __shared__ int h[DEGB];
    __shared__ int base[DEGB];
    int b = blockIdx.x, t = threadIdx.x;

    // (1) s0 = sum btot[0..b-1]  (bucket base in ebuf)
    tmp[t] = (t < b) ? btot[t] : 0;
    __syncthreads();
    #pragma unroll
    for (int o = 128; o > 0; o >>= 1) {
        if (t < o) tmp[t] += tmp[t + o];
        __syncthreads();
    }
    const int s0 = tmp[0];
    __syncthreads();

    // (2) roff = sum partials[0..b-1]  (global rowstart offset)
    tmp[t] = (t < b) ? partials[t] : 0;
    __syncthreads();
    #pragma unroll
    for (int o = 128; o > 0; o >>= 1) {
        if (t < o) tmp[t] += tmp[t + o];
        __syncthreads();
    }
    const int roff = tmp[0];
    __syncthreads();

    // (3) descending dstart from a full 512-wide inclusive scan of dhist
    h[t]       = dhist[t];
    h[t + 256] = dhist[t + 256];
    __syncthreads();
    for (int o = 1; o < DEGB; o <<= 1) {
        int v0 = (t >= o) ? h[t - o] : 0;
        int v1 = (t + 256 >= o) ? h[t + 256 - o] : 0;
        __syncthreads();
        h[t] += v0;
        h[t + 256] += v1;
        __syncthreads();
    }
    int total = h[DEGB - 1];
    base[t]       = total - h[t];
    base[t + 256] = total - h[t + 256];
    __syncthreads();

    // (4) CSR scatter with LDS cursors (global rowstart = block-local + roff)
    h[t] = 0; h[t + 256] = 0;           // reuse as rank histogram
    int node = b * 256 + t;
    int rs = (node < N) ? rowstart[node] + roff : 0;
    cur[t] = rs;
    __syncthreads();
    const int c = btot[b];
    for (int i = t; i < c; i += 256) {
        unsigned v = ebuf[s0 + i];
        int pos = atomicAdd(&cur[v >> 17], 1);
        csr_src[pos] = (int)(v & 0x1FFFFu);
    }
    int dv = (node < N) ? deg[node] : 0;
    int dc = dv < DEGB - 1 ? dv : DEGB - 1;
    int r = 0;
    if (node < N) r = atomicAdd(&h[dc], 1);
    __syncthreads();
    int c0 = h[t];       if (c0) base[t]       += atomicAdd(&dcur[t], c0);
    int c1 = h[t + 256]; if (c1) base[t + 256] += atomicAdd(&dcur[t + 256], c1);
    __syncthreads();
    if (node < N) desc[base[dc] + r] = make_int4(node, rs, dv, 0);
}

// ---------------- split-bf16 MFMA GEMM (+ optional fused bucket_hist) ----------------
// out[N x MOUT] (per W-side) = A[N x 128] @ W.
// A@W ~= Ah@Wh + Ah@Wlo + Al@Wh  (lo*lo dropped, ~2^-18 relative).
// blockIdx decodes: first histBlocks blocks run the CSR bucket histogram
// (independent work, hidden under the gemm — R13); the rest do the gemm with
// g = blockIdx.x - histBlocks, row tile g>>1, W-side g&1. Each block computes
// ALL MOUT cols of its W (A read once per W-side; R12). Hist's 1KB LDS
// aliases into Bh (roles are mutually exclusive) to stay at the 64KB cap.
template<int MOUT, bool CONVA>
__global__ __launch_bounds__(256) void gemm_mfma(const ushort_t* __restrict__ Ah,
                                                 const ushort_t* __restrict__ Al,
                                                 const float* __restrict__ Af,
                                                 const float* __restrict__ Wl,
                                                 const float* __restrict__ Wr,
                                                 ushort_t* __restrict__ xlh,
                                                 ushort_t* __restrict__ xrh, int N,
                                                 const int* __restrict__ ei,
                                                 int E, int Et,
                                                 int* __restrict__ blkcnt,
                                                 int histBlocks) {
    constexpr int NT  = MOUT / 16;      // 16-col tiles: 8 (MOUT=128) / 4 (64)
    constexpr int FPT = MOUT / 8;       // float4 loads per thread
    constexpr int CPR = MOUT / 4;       // float4 columns per k-row
    __shared__ __align__(16) ushort_t Bh[NT * 2048];   // NT*4KB
    __shared__ __align__(16) ushort_t Bl[NT * 2048];
    const int tid = threadIdx.x;

    if ((int)blockIdx.x < histBlocks) {
        // ---- fused bucket_hist: 256-bin histogram of dst>>8 per 4096 edges ----
        int* cnt = (int*)Bh;            // alias: hist blocks never run the gemm
        cnt[tid] = 0;
        __syncthreads();
        int e0 = blockIdx.x * EB;
        #pragma unroll
        for (int it = 0; it < EB / 256; ++it) {
            int e = e0 + it * 256 + tid;
            if (e < Et) {
                int d = (e < E) ? ei[E + e] : (e - E);
                atomicAdd(&cnt[d >> 8], 1);
            }
        }
        __syncthreads();
        blkcnt[blockIdx.x * 256 + tid] = cnt[tid];
        return;
    }

    const int g     = (int)blockIdx.x - histBlocks;
    const int row0  = (g >> 1) * 128;
    const bool isR  = (g & 1) != 0;
    const float* W  = isR ? Wr : Wl;
    ushort_t* OUT   = isR ? xrh : xlh;

    #pragma unroll
    for (int i = 0; i < FPT; ++i) {
        int idx = tid * FPT + i;
        int k   = idx / CPR;
        int c4  = (idx % CPR) * 4;
        float4 w = *(const float4*)(W + (size_t)k * MOUT + c4);
        float wv[4] = {w.x, w.y, w.z, w.w};
        int q = k >> 5, quad = (k >> 3) & 3, j = k & 7;
        #pragma unroll
        for (int e = 0; e < 4; ++e) {
            int c = c4 + e;
            int t = c >> 4;
            int l = (quad << 4) | (c & 15);
            int pos = ((t * 4 + q) * 64 + l) * 8 + j;
            ushort_t hb = f2bf(wv[e]);
            Bh[pos] = hb;
            Bl[pos] = f2bf(wv[e] - bf2f(hb));
        }
    }
    __syncthreads();

    const int wv_  = tid >> 6;
    const int lane = tid & 63;
    const int m    = lane & 15;
    const int quad = lane >> 4;
    const int wrow0 = row0 + wv_ * 32;

    f32x4 acc[2][NT] = {};

    for (int q = 0; q < 4; ++q) {
        short8 ahf[2], alf[2];
        #pragma unroll
        for (int r = 0; r < 2; ++r) {
            int row = wrow0 + 16 * r + m;
            row = row < N ? row : N - 1;
            size_t off = (size_t)row * 128 + q * 32 + quad * 8;
            if constexpr (CONVA) {
                float4 f0 = *(const float4*)(Af + off);
                float4 f1 = *(const float4*)(Af + off + 4);
                float fv[8] = {f0.x, f0.y, f0.z, f0.w, f1.x, f1.y, f1.z, f1.w};
                short ah[8], al[8];
                #pragma unroll
                for (int e = 0; e < 8; ++e) {
                    ushort_t hb = f2bf(fv[e]);
                    ah[e] = (short)hb;
                    al[e] = (short)f2bf(fv[e] - bf2f(hb));
                }
                ahf[r] = short8{ah[0],ah[1],ah[2],ah[3],ah[4],ah[5],ah[6],ah[7]};
                alf[r] = short8{al[0],al[1],al[2],al[3],al[4],al[5],al[6],al[7]};
            } else {
                ahf[r] = *(const short8*)(Ah + off);
                alf[r] = *(const short8*)(Al + off);
            }
        }
        #pragma unroll
        for (int t = 0; t < NT; ++t) {
            int base = ((t * 4 + q) * 64 + lane) * 8;
            short8 bh = *(const short8*)(Bh + base);
            short8 bl = *(const short8*)(Bl + base);
            #pragma unroll
            for (int r = 0; r < 2; ++r) {
                acc[r][t] = __builtin_amdgcn_mfma_f32_16x16x32_bf16(ahf[r], bh, acc[r][t], 0, 0, 0);
                acc[r][t] = __builtin_amdgcn_mfma_f32_16x16x32_bf16(ahf[r], bl, acc[r][t], 0, 0, 0);
                acc[r][t] = __builtin_amdgcn_mfma_f32_16x16x32_bf16(alf[r], bh, acc[r][t], 0, 0, 0);
            }
        }
    }

    #pragma unroll
    for (int r = 0; r < 2; ++r)
        #pragma unroll
        for (int i = 0; i < 4; ++i) {
            int row = wrow0 + 16 * r + quad * 4 + i;
            if (row < N) {
                #pragma unroll
                for (int t = 0; t < NT; ++t)
                    OUT[(size_t)row * MOUT + t * 16 + m] = f2h(acc[r][t][i]);
            }
        }
}

// ---------------- fused per-node attention: one 16-lane group per node ----------------
// Best-known config (R10/R12): DR=5 (R11's DR=10 regressed), 1 node per
// group, full grid (R9's 2-node pipelining regressed), desc packed
// {node,rowstart,deg} setup = one 16B load.
template<int H, int C, bool ELU, int OMODE>
__global__ __launch_bounds__(512) void node_attn(const ushort_t* __restrict__ xlh,
                                                 const ushort_t* __restrict__ xrh,
                                                 const float* __restrict__ att,
                                                 const float* __restrict__ bias,
                                                 const int4* __restrict__ desc,
                                                 const int* __restrict__ csr_src,
                                                 int N, float* __restrict__ out,
                                                 ushort_t* __restrict__ outh,
                                                 ushort_t* __restrict__ outl) {
    constexpr int HC  = H * C;          // 128 / 64
    constexpr int VPT = 8;
    constexpr int LPG = HC / VPT;       // lanes per group: 16 / 8
    constexpr int GPW = 64 / LPG;       // groups (nodes) per wave: 4 / 8
    constexpr int GROUP = C / VPT;      // lanes per head: 4 / 8
    constexpr int DR  = 5;              // gather ring depth per group

    const int lane = threadIdx.x & 63;
    const int wv   = threadIdx.x >> 6;
    const int gid  = lane / LPG;
    const int lig  = lane % LPG;
    const int ch0  = lig * VPT;

    const int s = (blockIdx.x * 8 + wv) * GPW + gid;
    if (s >= N) return;

    // per-kernel invariants
    half2_t a2[4];
    {
        float4 u0 = *(const float4*)(att + ch0);
        float4 u1 = *(const float4*)(att + ch0 + 4);
        a2[0] = half2_t{(_Float16)u0.x, (_Float16)u0.y};
        a2[1] = half2_t{(_Float16)u0.z, (_Float16)u0.w};
        a2[2] = half2_t{(_Float16)u1.x, (_Float16)u1.y};
        a2[3] = half2_t{(_Float16)u1.z, (_Float16)u1.w};
    }
    float bias8[VPT];
    {
        float4 b0 = *(const float4*)(bias + ch0);
        float4 b1 = *(const float4*)(bias + ch0 + 4);
        bias8[0]=b0.x; bias8[1]=b0.y; bias8[2]=b0.z; bias8[3]=b0.w;
        bias8[4]=b1.x; bias8[5]=b1.y; bias8[6]=b1.z; bias8[7]=b1.w;
    }
    const half2_t c02 = half2_t{(_Float16)NEG_SLOPE, (_Float16)NEG_SLOPE};

    const int4 dsc = desc[s];
    const int n  = dsc.x;
    const int j0 = dsc.y;
    const int dg = dsc.z;               // >= 1 (self-loop)

    half8 xrv = *(const half8*)(xrh + (size_t)n * HC + ch0);

    auto ldidx = [&](int e) {
        int ee = e < dg ? e : dg - 1;   // clamp: harmless duplicate loads
        return csr_src[j0 + ee];
    };
    auto ldrow = [&](int idx) -> half8 {
        return *(const half8*)(xlh + (size_t)(unsigned)idx * HC + ch0);  // 16 B
    };

    float d = 0.f;
    float acc[VPT] = {};

    auto process = [&](half8 v) {
        float p = 0.f;
        #pragma unroll
        for (int i = 0; i < 4; ++i) {
            half2_t v2 = half2_t{v[2 * i], v[2 * i + 1]};
            half2_t x2 = half2_t{xrv[2 * i], xrv[2 * i + 1]};
            half2_t m2 = v2 + x2;                                 // v_pk_add_f16
            half2_t lr = __builtin_elementwise_max(m2, c02 * m2); // pk_mul+pk_max
            p = dot2acc(lr, a2[i], p);                            // v_dot2_f32_f16
        }
        // head reduce: quad DPP (lanes of one head are an aligned quad),
        // plus lane^4 swizzle when the head spans 8 lanes (layer 3).
        if constexpr (GROUP >= 2) p = dpp_add<0xB1>(p);  // xor 1
        if constexpr (GROUP >= 4) p = dpp_add<0x4E>(p);  // xor 2
        if constexpr (GROUP >= 8) p = swz4_add(p);       // xor 4
        float pe = __expf(p);
        d += pe;
        #pragma unroll
        for (int i = 0; i < VPT; ++i)
            acc[i] += pe * (float)v[i];                           // fma_mix-able
    };

    // ring prologue: indices, then rows (+ next indices)
    int   ibuf[DR];
    half8 rbuf[DR];
    #pragma unroll
    for (int k = 0; k < DR; ++k) ibuf[k] = ldidx(k);
    #pragma unroll
    for (int k = 0; k < DR; ++k) {
        rbuf[k] = ldrow(ibuf[k]);
        ibuf[k] = ldidx(k + DR);
    }

    int e = 0;
    for (; e + DR <= dg; e += DR) {      // group-uniform trip count
        #pragma unroll
        for (int k = 0; k < DR; ++k) {
            half8 v = rbuf[k];
            rbuf[k] = ldrow(ibuf[k]);
            ibuf[k] = ldidx(e + k + 2 * DR);
            process(v);
        }
    }
    #pragma unroll
    for (int k = 0; k < DR; ++k)
        if (e + k < dg) process(rbuf[k]);

    // epilogue: d and acc are lane-local (d uniform across the head's lanes)
    float inv = 1.f / d;
    float vv[VPT];
    #pragma unroll
    for (int i = 0; i < VPT; ++i) {
        float v = acc[i] * inv + bias8[i];
        if (ELU) v = v > 0.f ? v : (__expf(v) - 1.f);
        vv[i] = v;
    }
    if (OMODE == 0) {
        *(float4*)(out + (size_t)n * HC + ch0) =
            make_float4(vv[0], vv[1], vv[2], vv[3]);
        *(float4*)(out + (size_t)n * HC + ch0 + 4) =
            make_float4(vv[4], vv[5], vv[6], vv[7]);
    } else {
        ushort_t hb[VPT], lb[VPT];
        #pragma unroll
        for (int i = 0; i < VPT; ++i) {
            hb[i] = f2bf(vv[i]);
            lb[i] = f2bf(vv[i] - bf2f(hb[i]));
        }
        *(ushort4*)(outh + (size_t)n * HC + ch0) =
            ushort4{hb[0], hb[1], hb[2], hb[3]};
        *(ushort4*)(outh + (size_t)n * HC + ch0 + 4) =
            ushort4{hb[4], hb[5], hb[6], hb[7]};
        *(ushort4*)(outl + (size_t)n * HC + ch0) =
            ushort4{lb[0], lb[1], lb[2], lb[3]};
        *(ushort4*)(outl + (size_t)n * HC + ch0 + 4) =
            ushort4{lb[4], lb[5], lb[6], lb[7]};
    }
}

// ---------------- launch ----------------
extern "C" void kernel_launch(void* const* d_in, const int* in_sizes, int n_in,
                              void* d_out, int out_size, void* d_ws, size_t ws_size,
                              hipStream_t stream) {
    const float* x   = (const float*)d_in[0];
    const int*   ei  = (const int*)d_in[1];
    const float* Wl1 = (const float*)d_in[2];
    const float* Wr1 = (const float*)d_in[3];
    const float* a1  = (const float*)d_in[4];
    const float* b1  = (const float*)d_in[5];
    const float* Wl2 = (const float*)d_in[6];
    const float* Wr2 = (const float*)d_in[7];
    const float* a2  = (const float*)d_in[8];
    const float* b2  = (const float*)d_in[9];
    const float* Wl3 = (const float*)d_in[10];
    const float* Wr3 = (const float*)d_in[11];
    const float* a3  = (const float*)d_in[12];
    const float* b3  = (const float*)d_in[13];

    const int N  = in_sizes[0] / 128;   // 50000
    const int E  = in_sizes[1] / 2;     // 800000
    const int Et = E + N;               // 850000
    const int nb = (N + 255) / 256;     // 196 (= bucket count)

    char* p = (char*)d_ws;
    auto alloc = [&](size_t bytes) -> void* {
        void* r = (void*)p;
        p += (bytes + 255) & ~(size_t)255;
        return r;
    };
    const int ebBlocks = (Et + EB - 1) / EB;    // 208
    int*      csr_src  = (int*)alloc((size_t)Et * 4 + 256);
    unsigned* ebuf     = (unsigned*)alloc((size_t)Et * 4);
    int*      blkcnt   = (int*)alloc((size_t)ebBlocks * 256 * 4);
    int*      btot     = (int*)alloc(256 * 4);
    int*      deg      = (int*)alloc((size_t)N * 4);
    int*      rowstart = (int*)alloc((size_t)N * 4);
    int*      partials = (int*)alloc((size_t)nb * 4);
    int4*     desc     = (int4*)alloc((size_t)N * 16);
    int*      dhist    = (int*)alloc((size_t)DEGB * 4);
    int*      dcur     = (int*)alloc((size_t)DEGB * 4);
    ushort_t* xlh      = (ushort_t*)alloc((size_t)N * 128 * 2);  // fp16 gather table
    ushort_t* xrh      = (ushort_t*)alloc((size_t)N * 128 * 2);  // fp16 target table
    ushort_t* Ah       = (ushort_t*)alloc((size_t)N * 128 * 2);
    ushort_t* Al       = (ushort_t*)alloc((size_t)N * 128 * 2);

    const int rowBlocks    = (N + 127) / 128;   // 391
    const int nodeBlocks12 = (N + 31) / 32;     // 1 node per 16-lane group
    const int nodeBlocks3  = (N + 63) / 64;     // 1 node per 8-lane group

    // ---- layer-1 gemm + fused CSR bucket histogram (independent work) ----
    gemm_mfma<128, true><<<ebBlocks + rowBlocks * 2, 256, 0, stream>>>(
        nullptr, nullptr, x, Wl1, Wr1, xlh, xrh, N, ei, E, Et, blkcnt, ebBlocks);

    // ---- rest of the bucketed CSR build (reused by all layers) ----
    colscan<<<256, 64, 0, stream>>>(blkcnt, ebBlocks, btot, dhist, dcur);
    bucket_scatter<<<ebBlocks, 256, 0, stream>>>(ei, E, Et, blkcnt, btot, ebuf);
    bucket_deg_scan_hist<<<nb, 256, 0, stream>>>(ebuf, btot, N,
                                                 deg, rowstart, partials, dhist);
    csr_perm_scatter<<<nb, 256, 0, stream>>>(ebuf, btot, rowstart, partials,
                                             deg, N, dhist, dcur, csr_src, desc);

    // ---- layer 1 attention ----
    node_attn<4, 32, true, 1><<<nodeBlocks12, 512, 0, stream>>>(
        xlh, xrh, a1, b1, desc, csr_src, N, nullptr, Ah, Al);

    // ---- layer 2: 128 -> 4x32, concat, ELU ----
    gemm_mfma<128, false><<<rowBlocks * 2, 256, 0, stream>>>(
        Ah, Al, nullptr, Wl2, Wr2, xlh, xrh, N, nullptr, 0, 0, nullptr, 0);
    node_attn<4, 32, true, 1><<<nodeBlocks12, 512, 0, stream>>>(
        xlh, xrh, a2, b2, desc, csr_src, N, nullptr, Ah, Al);

    // ---- layer 3: 128 -> 64, heads=1, concat=False ----
    float* out = (float*)d_out;
    gemm_mfma<64, false><<<rowBlocks * 2, 256, 0, stream>>>(
        Ah, Al, nullptr, Wl3, Wr3, xlh, xrh, N, nullptr, 0, 0, nullptr, 0);
    node_attn<1, 64, false, 0><<<nodeBlocks3, 512, 0, stream>>>(
        xlh, xrh, a3, b3, desc, csr_src, N, out, nullptr, nullptr);
}